// Round 1
// baseline (2953.174 us; speedup 1.0000x reference)
//
#include <hip/hip_runtime.h>
#include <math.h>

static constexpr int NN = 8192;      // nodes
static constexpr int NE = 262144;    // edges
static constexpr int NCH = 32;       // K-chunks for flash partials
static constexpr int CHR = NN / NCH; // 256 K-rows per chunk

// ---------------- graph prep ----------------

__global__ void k_count(const int* __restrict__ dst, int* __restrict__ indeg) {
  int t = blockIdx.x * 256 + threadIdx.x;
  if (t < NE) atomicAdd(&indeg[dst[t]], 1);
}

__global__ void k_scan(const int* __restrict__ indeg, int* __restrict__ off,
                       int* __restrict__ cur, float* __restrict__ dinv) {
  __shared__ int sh[1024];
  __shared__ int carry;
  int t = threadIdx.x;
  if (t == 0) carry = 0;
  __syncthreads();
  for (int base = 0; base < NN; base += 1024) {
    int v = indeg[base + t];
    sh[t] = v;
    __syncthreads();
    for (int s = 1; s < 1024; s <<= 1) {
      int add = (t >= s) ? sh[t - s] : 0;
      __syncthreads();
      sh[t] += add;
      __syncthreads();
    }
    int excl = carry + sh[t] - v;
    off[base + t] = excl;
    cur[base + t] = excl;
    dinv[base + t] = 1.0f / sqrtf((float)(v + 1));  // +1 self loop
    __syncthreads();
    if (t == 1023) carry += sh[t];
    __syncthreads();
  }
  if (t == 0) off[NN] = carry;
}

__global__ void k_fill(const int* __restrict__ src, const int* __restrict__ dst,
                       int* __restrict__ cur, int* __restrict__ srcl) {
  int t = blockIdx.x * 256 + threadIdx.x;
  if (t < NE) {
    int d = dst[t];
    int slot = atomicAdd(&cur[d], 1);
    srcl[slot] = src[t];
  }
}

// ---------------- dense f32 GEMM: C[M x N] = A[M x K] @ B[K x N] ----------------

template <int K, int N>
__global__ __launch_bounds__(256) void k_gemm(const float* __restrict__ A,
                                              const float* __restrict__ B,
                                              float* __restrict__ C) {
  constexpr int ROWS = 256 / N;
  __shared__ float ash[ROWS * K];
  int r0 = blockIdx.x * ROWS;
  for (int i = threadIdx.x; i < ROWS * K; i += 256) ash[i] = A[r0 * K + i];
  __syncthreads();
  int col = threadIdx.x % N;
  int r = threadIdx.x / N;
  float acc = 0.f;
#pragma unroll 8
  for (int k = 0; k < K; ++k) acc += ash[r * K + k] * B[k * N + col];
  C[(size_t)(r0 + r) * N + col] = acc;
}

// ---------------- GCN aggregation: out[d] = dinv[d]*(sum_s dinv[s]*xw[s]) + b ----------------

template <int D, bool RELU>
__global__ __launch_bounds__(256) void k_agg(const float* __restrict__ xw,
                                             const int* __restrict__ off,
                                             const int* __restrict__ srcl,
                                             const float* __restrict__ dinv,
                                             const float* __restrict__ bias,
                                             float* __restrict__ out) {
  constexpr int NPB = 256 / D;
  int node = blockIdx.x * NPB + threadIdx.x / D;
  int d = threadIdx.x % D;
  float dn = dinv[node];
  int s0 = off[node], s1 = off[node + 1];
  float acc = dn * xw[(size_t)node * D + d];  // self loop (dinv[n]^2 * xw[n])
  for (int p = s0; p < s1; ++p) {
    int s = srcl[p];
    acc += dinv[s] * xw[(size_t)s * D + d];
  }
  float r = dn * acc + bias[d];
  if (RELU) r = fmaxf(r, 0.f);
  out[(size_t)node * D + d] = r;
}

// ---------------- flash attention partials (f32, one Q-row per thread) ----------------

__global__ __launch_bounds__(256) void k_attn_part(const float* __restrict__ Q,
                                                   const float* __restrict__ Km,
                                                   const float* __restrict__ Vm,
                                                   float* __restrict__ Opart,
                                                   float* __restrict__ mpart,
                                                   float* __restrict__ lpart) {
  int row = blockIdx.x * 256 + threadIdx.x;
  int ch = blockIdx.y;
  const float4* q4 = (const float4*)(Q + (size_t)row * 64);
  float4 q[16], o[16];
#pragma unroll
  for (int i = 0; i < 16; ++i) {
    q[i] = q4[i];
    o[i] = make_float4(0.f, 0.f, 0.f, 0.f);
  }
  float m = -1e30f, l = 0.f;
  int j0 = ch * CHR;
  for (int j = j0; j < j0 + CHR; ++j) {
    const float4* k4 = (const float4*)(Km + (size_t)j * 64);
    float s = 0.f;
#pragma unroll
    for (int i = 0; i < 16; ++i) {
      float4 kv = k4[i];
      s += q[i].x * kv.x + q[i].y * kv.y + q[i].z * kv.z + q[i].w * kv.w;
    }
    s = fmaxf(s, 0.01f * s);  // leaky_relu(0.01)
    if (s > m + 4.f) {        // lazy rescale, p bounded by e^4
      float corr = __expf(m - s);
      l *= corr;
#pragma unroll
      for (int i = 0; i < 16; ++i) {
        o[i].x *= corr; o[i].y *= corr; o[i].z *= corr; o[i].w *= corr;
      }
      m = s;
    }
    float p = __expf(s - m);
    l += p;
    const float4* v4 = (const float4*)(Vm + (size_t)j * 64);
#pragma unroll
    for (int i = 0; i < 16; ++i) {
      float4 vv = v4[i];
      o[i].x += p * vv.x; o[i].y += p * vv.y; o[i].z += p * vv.z; o[i].w += p * vv.w;
    }
  }
  float4* op = (float4*)(Opart + ((size_t)ch * NN + row) * 64);
#pragma unroll
  for (int i = 0; i < 16; ++i) op[i] = o[i];
  mpart[ch * NN + row] = m;
  lpart[ch * NN + row] = l;
}

__global__ void k_attn_comb(const float* __restrict__ Opart,
                            const float* __restrict__ mpart,
                            const float* __restrict__ lpart,
                            float* __restrict__ O) {
  int row = blockIdx.x;
  int d = threadIdx.x;  // 64 threads
  float M = -1e30f;
  for (int i = 0; i < NCH; ++i) M = fmaxf(M, mpart[i * NN + row]);
  float L = 0.f, acc = 0.f;
  for (int i = 0; i < NCH; ++i) {
    float w = __expf(mpart[i * NN + row] - M);
    L += w * lpart[i * NN + row];
    acc += w * Opart[((size_t)i * NN + row) * 64 + d];
  }
  O[(size_t)row * 64 + d] = acc / L;
}

// ---------------- logits = o1 @ o2^T  (lane owns o2 row -> coalesced stores) ----------------

__global__ __launch_bounds__(256) void k_outer(const float* __restrict__ o1,
                                               const float* __restrict__ o2,
                                               float* __restrict__ out) {
  int wave = threadIdx.x >> 6, lane = threadIdx.x & 63;
  int j = (blockIdx.x * 4 + wave) * 64 + lane;
  const float4* b4 = (const float4*)(o2 + (size_t)j * 64);
  float4 b[16];
#pragma unroll
  for (int i = 0; i < 16; ++i) b[i] = b4[i];
  int i0 = blockIdx.y * (NN / 16);
  for (int i = i0; i < i0 + NN / 16; ++i) {
    const float4* a4 = (const float4*)(o1 + (size_t)i * 64);
    float acc = 0.f;
#pragma unroll
    for (int t = 0; t < 16; ++t) {
      float4 av = a4[t];
      acc += av.x * b[t].x + av.y * b[t].y + av.z * b[t].z + av.w * b[t].w;
    }
    out[(size_t)i * NN + j] = acc;
  }
}

// ---------------- launch ----------------

extern "C" void kernel_launch(void* const* d_in, const int* in_sizes, int n_in,
                              void* d_out, int out_size, void* d_ws, size_t ws_size,
                              hipStream_t stream) {
  const int* g1 = (const int*)d_in[0];
  const int* g2 = (const int*)d_in[1];
  const float* x1 = (const float*)d_in[2];
  const float* x2 = (const float*)d_in[3];
  const float* W11 = (const float*)d_in[4];
  const float* b11 = (const float*)d_in[5];
  const float* W12 = (const float*)d_in[6];
  const float* b12 = (const float*)d_in[7];
  const float* W21 = (const float*)d_in[8];
  const float* b21 = (const float*)d_in[9];
  const float* W22 = (const float*)d_in[10];
  const float* b22 = (const float*)d_in[11];
  const float* q1 = (const float*)d_in[12];
  const float* k1 = (const float*)d_in[13];
  const float* v1 = (const float*)d_in[14];
  const float* q2 = (const float*)d_in[15];
  const float* k2 = (const float*)d_in[16];
  const float* v2 = (const float*)d_in[17];

  // d_out (256 MB) doubles as scratch for everything that dies before the
  // final outer-product GEMM (which overwrites all of it). Only o1/o2 persist
  // into that GEMM -> they live in d_ws (4 MB needed).
  char* ob = (char*)d_out;
  float* bufA = (float*)(ob);                      // 8 MB  (xw, 8192x256)
  float* bufB = (float*)(ob + (8u << 20));         // 8 MB  (h, 8192x256)
  int* srcl1 = (int*)(ob + (16u << 20));           // 1 MB
  int* srcl2 = (int*)(ob + (17u << 20));           // 1 MB
  char* small = ob + (18u << 20);
  int* ideg1 = (int*)(small);
  int* ideg2 = (int*)(small + (64u << 10));
  int* off1 = (int*)(small + (128u << 10));
  int* off2 = (int*)(small + (192u << 10));
  int* cur1 = (int*)(small + (256u << 10));
  int* cur2 = (int*)(small + (320u << 10));
  float* dinv1 = (float*)(small + (384u << 10));
  float* dinv2 = (float*)(small + (448u << 10));
  float* Qb = (float*)(ob + (19u << 20));          // 2 MB
  float* Kb = (float*)(ob + (21u << 20));          // 2 MB
  float* Vb = (float*)(ob + (23u << 20));          // 2 MB
  float* Opart = (float*)(ob + (25u << 20));       // 64 MB (32 x 8192 x 64)
  float* mpart = (float*)(ob + (90u << 20));       // 1 MB
  float* lpart = (float*)(ob + (91u << 20));       // 1 MB
  float* h1b = (float*)(ob + (93u << 20));         // 2 MB
  float* h2b = (float*)(ob + (95u << 20));         // 2 MB
  float* o1 = (float*)d_ws;                        // 2 MB (persists)
  float* o2 = (float*)((char*)d_ws + (2u << 20));  // 2 MB (persists)

  hipMemsetAsync(ideg1, 0, NN * 4, stream);
  hipMemsetAsync(ideg2, 0, NN * 4, stream);
  dim3 eb((NE + 255) / 256);
  k_count<<<eb, 256, 0, stream>>>(g1 + NE, ideg1);
  k_count<<<eb, 256, 0, stream>>>(g2 + NE, ideg2);
  k_scan<<<1, 1024, 0, stream>>>(ideg1, off1, cur1, dinv1);
  k_scan<<<1, 1024, 0, stream>>>(ideg2, off2, cur2, dinv2);
  k_fill<<<eb, 256, 0, stream>>>(g1, g1 + NE, cur1, srcl1);
  k_fill<<<eb, 256, 0, stream>>>(g2, g2 + NE, cur2, srcl2);

  // GCN branch 1
  k_gemm<128, 256><<<NN, 256, 0, stream>>>(x1, W11, bufA);
  k_agg<256, true><<<NN, 256, 0, stream>>>(bufA, off1, srcl1, dinv1, b11, bufB);
  k_gemm<256, 64><<<NN / 4, 256, 0, stream>>>(bufB, W12, bufA);
  k_agg<64, false><<<NN / 4, 256, 0, stream>>>(bufA, off1, srcl1, dinv1, b12, h1b);
  // GCN branch 2
  k_gemm<128, 256><<<NN, 256, 0, stream>>>(x2, W21, bufA);
  k_agg<256, true><<<NN, 256, 0, stream>>>(bufA, off2, srcl2, dinv2, b21, bufB);
  k_gemm<256, 64><<<NN / 4, 256, 0, stream>>>(bufB, W22, bufA);
  k_agg<64, false><<<NN / 4, 256, 0, stream>>>(bufA, off2, srcl2, dinv2, b22, h2b);

  // cross attention 1: Q=h1b@q1, K=h2b@k1, V=h1b@v1 -> o1
  k_gemm<64, 64><<<NN / 4, 256, 0, stream>>>(h1b, q1, Qb);
  k_gemm<64, 64><<<NN / 4, 256, 0, stream>>>(h2b, k1, Kb);
  k_gemm<64, 64><<<NN / 4, 256, 0, stream>>>(h1b, v1, Vb);
  dim3 ag(NN / 256, NCH);
  k_attn_part<<<ag, 256, 0, stream>>>(Qb, Kb, Vb, Opart, mpart, lpart);
  k_attn_comb<<<NN, 64, 0, stream>>>(Opart, mpart, lpart, o1);

  // cross attention 2: Q=h2b@q2, K=o1@k2, V=h2b@v2 -> o2
  k_gemm<64, 64><<<NN / 4, 256, 0, stream>>>(h2b, q2, Qb);
  k_gemm<64, 64><<<NN / 4, 256, 0, stream>>>(o1, k2, Kb);
  k_gemm<64, 64><<<NN / 4, 256, 0, stream>>>(h2b, v2, Vb);
  k_attn_part<<<ag, 256, 0, stream>>>(Qb, Kb, Vb, Opart, mpart, lpart);
  k_attn_comb<<<NN, 64, 0, stream>>>(Opart, mpart, lpart, o2);

  // logits = o1 @ o2^T -> d_out (overwrites all scratch regions)
  dim3 og(NN / 256, 16);
  k_outer<<<og, 256, 0, stream>>>(o1, o2, (float*)d_out);

  (void)in_sizes; (void)n_in; (void)out_size; (void)ws_size;
}

// Round 2
// 1335.630 us; speedup vs baseline: 2.2111x; 2.2111x over previous
//
#include <hip/hip_runtime.h>
#include <math.h>

static constexpr int NN = 8192;      // nodes
static constexpr int NE = 262144;    // edges
static constexpr int NCH = 8;        // K-chunks for flash partials

typedef short bfrag __attribute__((ext_vector_type(8)));   // 8 bf16 (A/B frag)
typedef float f32x4 __attribute__((ext_vector_type(4)));   // C/D frag

#define MFMA(a, b, c) __builtin_amdgcn_mfma_f32_16x16x32_bf16((a), (b), (c), 0, 0, 0)

__device__ __forceinline__ unsigned short f2bf(float x) {
  union { float f; unsigned u; } v; v.f = x;
  unsigned r = v.u + 0x7fffu + ((v.u >> 16) & 1u);  // RNE
  return (unsigned short)(r >> 16);
}
__device__ __forceinline__ float bf2f(unsigned short h) {
  union { unsigned u; float f; } v; v.u = ((unsigned)h) << 16;
  return v.f;
}

// ---------------- graph prep ----------------

__global__ void k_count(const int* __restrict__ dst, int* __restrict__ indeg) {
  int t = blockIdx.x * 256 + threadIdx.x;
  if (t < NE) atomicAdd(&indeg[dst[t]], 1);
}

__global__ void k_scan(const int* __restrict__ indeg, int* __restrict__ off,
                       int* __restrict__ cur, float* __restrict__ dinv) {
  __shared__ int sh[1024];
  __shared__ int carry;
  int t = threadIdx.x;
  if (t == 0) carry = 0;
  __syncthreads();
  for (int base = 0; base < NN; base += 1024) {
    int v = indeg[base + t];
    sh[t] = v;
    __syncthreads();
    for (int s = 1; s < 1024; s <<= 1) {
      int add = (t >= s) ? sh[t - s] : 0;
      __syncthreads();
      sh[t] += add;
      __syncthreads();
    }
    int excl = carry + sh[t] - v;
    off[base + t] = excl;
    cur[base + t] = excl;
    dinv[base + t] = 1.0f / sqrtf((float)(v + 1));  // +1 self loop
    __syncthreads();
    if (t == 1023) carry += sh[t];
    __syncthreads();
  }
  if (t == 0) off[NN] = carry;
}

__global__ void k_fill(const int* __restrict__ src, const int* __restrict__ dst,
                       int* __restrict__ cur, int* __restrict__ srcl) {
  int t = blockIdx.x * 256 + threadIdx.x;
  if (t < NE) {
    int d = dst[t];
    int slot = atomicAdd(&cur[d], 1);
    srcl[slot] = src[t];
  }
}

// ---------------- dense f32 GEMM: C[M x N] = A[M x K] @ B[K x N] ----------------

template <int K, int N>
__global__ __launch_bounds__(256) void k_gemm(const float* __restrict__ A,
                                              const float* __restrict__ B,
                                              float* __restrict__ C) {
  constexpr int ROWS = 256 / N;
  __shared__ float ash[ROWS * K];
  int r0 = blockIdx.x * ROWS;
  for (int i = threadIdx.x; i < ROWS * K; i += 256) ash[i] = A[r0 * K + i];
  __syncthreads();
  int col = threadIdx.x % N;
  int r = threadIdx.x / N;
  float acc = 0.f;
#pragma unroll 8
  for (int k = 0; k < K; ++k) acc += ash[r * K + k] * B[k * N + col];
  C[(size_t)(r0 + r) * N + col] = acc;
}

// ---------------- GCN aggregation ----------------

template <int D, bool RELU>
__global__ __launch_bounds__(256) void k_agg(const float* __restrict__ xw,
                                             const int* __restrict__ off,
                                             const int* __restrict__ srcl,
                                             const float* __restrict__ dinv,
                                             const float* __restrict__ bias,
                                             float* __restrict__ out) {
  int node = blockIdx.x * (256 / D) + threadIdx.x / D;
  int d = threadIdx.x % D;
  float dn = dinv[node];
  int s0 = off[node], s1 = off[node + 1];
  float acc = dn * xw[(size_t)node * D + d];  // self loop
  for (int p = s0; p < s1; ++p) {
    int s = srcl[p];
    acc += dinv[s] * xw[(size_t)s * D + d];
  }
  float r = dn * acc + bias[d];
  if (RELU) r = fmaxf(r, 0.f);
  out[(size_t)node * D + d] = r;
}

// ---------------- split f32 -> (hi, lo) bf16 ----------------

__global__ void k_split_rm(const float* __restrict__ X, short* __restrict__ hi,
                           short* __restrict__ lo) {
  int t = blockIdx.x * 256 + threadIdx.x;  // over NN*64
  float x = X[t];
  unsigned short h = f2bf(x);
  hi[t] = (short)h;
  lo[t] = (short)f2bf(x - bf2f(h));
}

// V (NN x 64) -> Vt hi/lo (64 x NN)
__global__ __launch_bounds__(256) void k_split_tr(const float* __restrict__ V,
                                                  short* __restrict__ Vthi,
                                                  short* __restrict__ Vtlo) {
  __shared__ float tile[64][65];
  int n0 = blockIdx.x * 64;
  int c = threadIdx.x & 63;
  int rb = threadIdx.x >> 6;
  for (int r = rb; r < 64; r += 4) tile[r][c] = V[(size_t)(n0 + r) * 64 + c];
  __syncthreads();
  for (int r = rb; r < 64; r += 4) {  // r = d index
    float x = tile[c][r];             // V[n0+c][r]
    unsigned short h = f2bf(x);
    Vthi[(size_t)r * NN + n0 + c] = (short)h;
    Vtlo[(size_t)r * NN + n0 + c] = (short)f2bf(x - bf2f(h));
  }
}

// ---------------- MFMA flash attention partials ----------------
// wave = 16 Q rows; block = 4 waves = 64 Q rows; grid = (NN/64, NCH)
// scores via bf16x3 (QhKh + QhKl + QlKh), PV via P_bf16 x (Vhi + Vlo)

__global__ __launch_bounds__(256) void k_attn_mfma(
    const short* __restrict__ Qhi, const short* __restrict__ Qlo,
    const short* __restrict__ Khi, const short* __restrict__ Klo,
    const short* __restrict__ Vthi, const short* __restrict__ Vtlo,
    float* __restrict__ Opart, float* __restrict__ mpart, float* __restrict__ lpart) {
  __shared__ short plds[4][16 * 40];  // per-wave P tile, row stride 40 bf16 (80B)
  int wave = threadIdx.x >> 6, lane = threadIdx.x & 63;
  int lo16 = lane & 15, hi4 = lane >> 4;
  int q0 = blockIdx.x * 64 + wave * 16;
  int ch = blockIdx.y;
  short* myp = plds[wave];

  // Q fragments: A[row=lo16][k=hi4*8+i], ksteps d=0..31 / 32..63
  const bfrag* qph = (const bfrag*)(Qhi + (q0 + lo16) * 64 + hi4 * 8);
  const bfrag* qpl = (const bfrag*)(Qlo + (q0 + lo16) * 64 + hi4 * 8);
  bfrag qh0 = qph[0], qh1 = qph[4];
  bfrag ql0 = qpl[0], ql1 = qpl[4];

  f32x4 z = {0.f, 0.f, 0.f, 0.f};
  f32x4 oacc[4] = {z, z, z, z};
  float mrun[4] = {-1e30f, -1e30f, -1e30f, -1e30f};
  float lsum[4] = {0.f, 0.f, 0.f, 0.f};

  int j0 = ch * (NN / NCH);
  for (int step = 0; step < (NN / NCH) / 32; ++step) {
    int jb = j0 + step * 32;
    // ---- scores: two 16-row K subtiles ----
    f32x4 sa[2];
#pragma unroll
    for (int t = 0; t < 2; ++t) {
      const bfrag* kph = (const bfrag*)(Khi + (jb + 16 * t + lo16) * 64 + hi4 * 8);
      const bfrag* kpl = (const bfrag*)(Klo + (jb + 16 * t + lo16) * 64 + hi4 * 8);
      bfrag kh0 = kph[0], kh1 = kph[4];
      bfrag kl0 = kpl[0], kl1 = kpl[4];
      f32x4 acc = z;
      acc = MFMA(qh0, kh0, acc);
      acc = MFMA(qh1, kh1, acc);
      acc = MFMA(qh0, kl0, acc);
      acc = MFMA(qh1, kl1, acc);
      acc = MFMA(ql0, kh0, acc);
      acc = MFMA(ql1, kh1, acc);
      sa[t] = acc;
    }
    // leaky_relu(0.01)
#pragma unroll
    for (int t = 0; t < 2; ++t)
#pragma unroll
      for (int r = 0; r < 4; ++r) {
        float v = sa[t][r];
        sa[t][r] = fmaxf(v, 0.01f * v);
      }
    // row max over the 32 cols of this step (cols live on lanes lo16, same hi4)
    float pm[4];
#pragma unroll
    for (int r = 0; r < 4; ++r) pm[r] = fmaxf(sa[0][r], sa[1][r]);
#pragma unroll
    for (int mask = 1; mask <= 8; mask <<= 1)
#pragma unroll
      for (int r = 0; r < 4; ++r) pm[r] = fmaxf(pm[r], __shfl_xor(pm[r], mask));
    // lazy rescale (defer-max, THR=4)
    bool rb = false;
#pragma unroll
    for (int r = 0; r < 4; ++r) rb |= (pm[r] > mrun[r] + 4.f);
    if (__any(rb)) {
#pragma unroll
      for (int r = 0; r < 4; ++r) {
        float nm = (pm[r] > mrun[r] + 4.f) ? pm[r] : mrun[r];
        float c_ = __expf(mrun[r] - nm);
        lsum[r] *= c_;
#pragma unroll
        for (int c = 0; c < 4; ++c) oacc[c][r] *= c_;
        mrun[r] = nm;
      }
    }
    // p = exp(s - m); accumulate per-lane partial row sums
    float p0[4], p1[4];
#pragma unroll
    for (int r = 0; r < 4; ++r) {
      p0[r] = __expf(sa[0][r] - mrun[r]);
      p1[r] = __expf(sa[1][r] - mrun[r]);
      lsum[r] += p0[r] + p1[r];
    }
    // write P tile (bf16) to per-wave LDS in C-layout, read back as A-frag
#pragma unroll
    for (int r = 0; r < 4; ++r) {
      int row = hi4 * 4 + r;
      myp[row * 40 + lo16] = (short)f2bf(p0[r]);
      myp[row * 40 + 16 + lo16] = (short)f2bf(p1[r]);
    }
    bfrag pa = *(const bfrag*)(myp + lo16 * 40 + hi4 * 8);
    // ---- PV: O += P(16x32) @ V(32x64), V from transposed split arrays ----
#pragma unroll
    for (int c = 0; c < 4; ++c) {
      bfrag vhf = *(const bfrag*)(Vthi + (size_t)(16 * c + lo16) * NN + jb + hi4 * 8);
      bfrag vlf = *(const bfrag*)(Vtlo + (size_t)(16 * c + lo16) * NN + jb + hi4 * 8);
      oacc[c] = MFMA(pa, vhf, oacc[c]);
      oacc[c] = MFMA(pa, vlf, oacc[c]);
    }
  }
  // reduce row sums across the 16 column-lanes
#pragma unroll
  for (int mask = 1; mask <= 8; mask <<= 1)
#pragma unroll
    for (int r = 0; r < 4; ++r) lsum[r] += __shfl_xor(lsum[r], mask);
  // store partials
#pragma unroll
  for (int c = 0; c < 4; ++c)
#pragma unroll
    for (int r = 0; r < 4; ++r)
      Opart[((size_t)ch * NN + q0 + hi4 * 4 + r) * 64 + 16 * c + lo16] = oacc[c][r];
  if (lo16 == 0) {
#pragma unroll
    for (int r = 0; r < 4; ++r) {
      mpart[ch * NN + q0 + hi4 * 4 + r] = mrun[r];
      lpart[ch * NN + q0 + hi4 * 4 + r] = lsum[r];
    }
  }
}

// combine partials -> O f32 (+ split bf16 for downstream MFMA consumers)
__global__ void k_attn_comb2(const float* __restrict__ Opart,
                             const float* __restrict__ mpart,
                             const float* __restrict__ lpart,
                             float* __restrict__ O, short* __restrict__ Ohi,
                             short* __restrict__ Olo) {
  int row = blockIdx.x * 4 + (threadIdx.x >> 6);
  int d = threadIdx.x & 63;
  float M = -1e30f;
  for (int i = 0; i < NCH; ++i) M = fmaxf(M, mpart[i * NN + row]);
  float L = 0.f, acc = 0.f;
  for (int i = 0; i < NCH; ++i) {
    float w = __expf(mpart[i * NN + row] - M);
    L += w * lpart[i * NN + row];
    acc += w * Opart[((size_t)i * NN + row) * 64 + d];
  }
  float o = acc / L;
  O[(size_t)row * 64 + d] = o;
  unsigned short h = f2bf(o);
  Ohi[(size_t)row * 64 + d] = (short)h;
  Olo[(size_t)row * 64 + d] = (short)f2bf(o - bf2f(h));
}

// ---------------- logits = o1 @ o2^T via bf16x3 MFMA ----------------
// wave = 16 i-rows; block = 4 waves; grid = (NN/64, 8) with j split 1024 each

__global__ __launch_bounds__(256) void k_outer_mfma(const short* __restrict__ o1hi,
                                                    const short* __restrict__ o1lo,
                                                    const short* __restrict__ o2hi,
                                                    const short* __restrict__ o2lo,
                                                    float* __restrict__ out) {
  int wave = threadIdx.x >> 6, lane = threadIdx.x & 63;
  int lo16 = lane & 15, hi4 = lane >> 4;
  int i0 = blockIdx.x * 64 + wave * 16;
  const bfrag* aph = (const bfrag*)(o1hi + (i0 + lo16) * 64 + hi4 * 8);
  const bfrag* apl = (const bfrag*)(o1lo + (i0 + lo16) * 64 + hi4 * 8);
  bfrag ah0 = aph[0], ah1 = aph[4];
  bfrag al0 = apl[0], al1 = apl[4];
  f32x4 z = {0.f, 0.f, 0.f, 0.f};
  int jbase = blockIdx.y * (NN / 8);
  for (int jt = 0; jt < (NN / 8) / 16; ++jt) {
    int j0 = jbase + jt * 16;
    const bfrag* bph = (const bfrag*)(o2hi + (j0 + lo16) * 64 + hi4 * 8);
    const bfrag* bpl = (const bfrag*)(o2lo + (j0 + lo16) * 64 + hi4 * 8);
    bfrag bh0 = bph[0], bh1 = bph[4];
    bfrag bl0 = bpl[0], bl1 = bpl[4];
    f32x4 acc = z;
    acc = MFMA(ah0, bh0, acc);
    acc = MFMA(ah1, bh1, acc);
    acc = MFMA(ah0, bl0, acc);
    acc = MFMA(ah1, bl1, acc);
    acc = MFMA(al0, bh0, acc);
    acc = MFMA(al1, bh1, acc);
#pragma unroll
    for (int r = 0; r < 4; ++r)
      out[(size_t)(i0 + hi4 * 4 + r) * NN + j0 + lo16] = acc[r];
  }
}

// ---------------- launch ----------------

extern "C" void kernel_launch(void* const* d_in, const int* in_sizes, int n_in,
                              void* d_out, int out_size, void* d_ws, size_t ws_size,
                              hipStream_t stream) {
  const int* g1 = (const int*)d_in[0];
  const int* g2 = (const int*)d_in[1];
  const float* x1 = (const float*)d_in[2];
  const float* x2 = (const float*)d_in[3];
  const float* W11 = (const float*)d_in[4];
  const float* b11 = (const float*)d_in[5];
  const float* W12 = (const float*)d_in[6];
  const float* b12 = (const float*)d_in[7];
  const float* W21 = (const float*)d_in[8];
  const float* b21 = (const float*)d_in[9];
  const float* W22 = (const float*)d_in[10];
  const float* b22 = (const float*)d_in[11];
  const float* q1 = (const float*)d_in[12];
  const float* k1 = (const float*)d_in[13];
  const float* v1 = (const float*)d_in[14];
  const float* q2 = (const float*)d_in[15];
  const float* k2 = (const float*)d_in[16];
  const float* v2 = (const float*)d_in[17];

  // d_out (256 MB) is scratch for everything that dies before k_outer_mfma.
  char* ob = (char*)d_out;
  float* bufA = (float*)(ob);                      // 8 MB
  float* bufB = (float*)(ob + (8u << 20));         // 8 MB
  int* srcl1 = (int*)(ob + (16u << 20));           // 1 MB
  int* srcl2 = (int*)(ob + (17u << 20));           // 1 MB
  char* small = ob + (18u << 20);
  int* ideg1 = (int*)(small);
  int* ideg2 = (int*)(small + (64u << 10));
  int* off1 = (int*)(small + (128u << 10));
  int* off2 = (int*)(small + (192u << 10));
  int* cur1 = (int*)(small + (256u << 10));
  int* cur2 = (int*)(small + (320u << 10));
  float* dinv1 = (float*)(small + (384u << 10));
  float* dinv2 = (float*)(small + (448u << 10));
  float* Qb = (float*)(ob + (19u << 20));          // 2 MB
  float* Kb = (float*)(ob + (21u << 20));          // 2 MB
  float* Vb = (float*)(ob + (23u << 20));          // 2 MB
  float* Opart = (float*)(ob + (25u << 20));       // 16 MB (8 x 8192 x 64)
  float* mpart = (float*)(ob + (41u << 20));       // 256 KB
  float* lpart = (float*)(ob + (42u << 20));       // 256 KB
  short* Qhi = (short*)(ob + (45u << 20));         // 1 MB each
  short* Qlo = (short*)(ob + (46u << 20));
  short* Khi = (short*)(ob + (47u << 20));
  short* Klo = (short*)(ob + (48u << 20));
  short* Vthi = (short*)(ob + (49u << 20));
  short* Vtlo = (short*)(ob + (50u << 20));
  float* o1f = (float*)(ob + (51u << 20));         // 2 MB
  float* o2f = (float*)(ob + (53u << 20));         // 2 MB
  float* h1b = (float*)(ob + (93u << 20));         // 2 MB
  float* h2b = (float*)(ob + (95u << 20));         // 2 MB
  // d_ws: only what k_outer_mfma consumes (4 MB)
  short* o1hi = (short*)d_ws;
  short* o1lo = (short*)((char*)d_ws + (1u << 20));
  short* o2hi = (short*)((char*)d_ws + (2u << 20));
  short* o2lo = (short*)((char*)d_ws + (3u << 20));

  hipMemsetAsync(ideg1, 0, NN * 4, stream);
  hipMemsetAsync(ideg2, 0, NN * 4, stream);
  dim3 eb((NE + 255) / 256);
  k_count<<<eb, 256, 0, stream>>>(g1 + NE, ideg1);
  k_count<<<eb, 256, 0, stream>>>(g2 + NE, ideg2);
  k_scan<<<1, 1024, 0, stream>>>(ideg1, off1, cur1, dinv1);
  k_scan<<<1, 1024, 0, stream>>>(ideg2, off2, cur2, dinv2);
  k_fill<<<eb, 256, 0, stream>>>(g1, g1 + NE, cur1, srcl1);
  k_fill<<<eb, 256, 0, stream>>>(g2, g2 + NE, cur2, srcl2);

  // GCN branch 1
  k_gemm<128, 256><<<NN, 256, 0, stream>>>(x1, W11, bufA);
  k_agg<256, true><<<NN, 256, 0, stream>>>(bufA, off1, srcl1, dinv1, b11, bufB);
  k_gemm<256, 64><<<NN / 4, 256, 0, stream>>>(bufB, W12, bufA);
  k_agg<64, false><<<NN / 4, 256, 0, stream>>>(bufA, off1, srcl1, dinv1, b12, h1b);
  // GCN branch 2
  k_gemm<128, 256><<<NN, 256, 0, stream>>>(x2, W21, bufA);
  k_agg<256, true><<<NN, 256, 0, stream>>>(bufA, off2, srcl2, dinv2, b21, bufB);
  k_gemm<256, 64><<<NN / 4, 256, 0, stream>>>(bufB, W22, bufA);
  k_agg<64, false><<<NN / 4, 256, 0, stream>>>(bufA, off2, srcl2, dinv2, b22, h2b);

  dim3 ag(NN / 64, NCH);
  // cross attention 1: Q=h1@q1, K=h2@k1, V=h1@v1 -> o1
  k_gemm<64, 64><<<NN / 4, 256, 0, stream>>>(h1b, q1, Qb);
  k_gemm<64, 64><<<NN / 4, 256, 0, stream>>>(h2b, k1, Kb);
  k_gemm<64, 64><<<NN / 4, 256, 0, stream>>>(h1b, v1, Vb);
  k_split_rm<<<NN * 64 / 256, 256, 0, stream>>>(Qb, Qhi, Qlo);
  k_split_rm<<<NN * 64 / 256, 256, 0, stream>>>(Kb, Khi, Klo);
  k_split_tr<<<NN / 64, 256, 0, stream>>>(Vb, Vthi, Vtlo);
  k_attn_mfma<<<ag, 256, 0, stream>>>(Qhi, Qlo, Khi, Klo, Vthi, Vtlo, Opart, mpart, lpart);
  k_attn_comb2<<<NN / 4, 256, 0, stream>>>(Opart, mpart, lpart, o1f, o1hi, o1lo);

  // cross attention 2: Q=h2@q2, K=o1@k2, V=h2@v2 -> o2
  k_gemm<64, 64><<<NN / 4, 256, 0, stream>>>(h2b, q2, Qb);
  k_gemm<64, 64><<<NN / 4, 256, 0, stream>>>(o1f, k2, Kb);
  k_gemm<64, 64><<<NN / 4, 256, 0, stream>>>(h2b, v2, Vb);
  k_split_rm<<<NN * 64 / 256, 256, 0, stream>>>(Qb, Qhi, Qlo);
  k_split_rm<<<NN * 64 / 256, 256, 0, stream>>>(Kb, Khi, Klo);
  k_split_tr<<<NN / 64, 256, 0, stream>>>(Vb, Vthi, Vtlo);
  k_attn_mfma<<<ag, 256, 0, stream>>>(Qhi, Qlo, Khi, Klo, Vthi, Vtlo, Opart, mpart, lpart);
  k_attn_comb2<<<NN / 4, 256, 0, stream>>>(Opart, mpart, lpart, o2f, o2hi, o2lo);

  // logits = o1 @ o2^T -> d_out (overwrites all scratch)
  dim3 og(NN / 64, 8);
  k_outer_mfma<<<og, 256, 0, stream>>>(o1hi, o1lo, o2hi, o2lo, (float*)d_out);

  (void)in_sizes; (void)n_in; (void)out_size; (void)ws_size;
}

// Round 3
// 764.804 us; speedup vs baseline: 3.8613x; 1.7464x over previous
//
#include <hip/hip_runtime.h>
#include <math.h>

static constexpr int NN = 8192;      // nodes
static constexpr int NE = 262144;    // edges
static constexpr int NCH = 8;        // K-chunks for flash partials
static constexpr int NS = (NN / NCH) / 32;  // 32 steps per chunk

typedef short bfrag __attribute__((ext_vector_type(8)));   // 8 bf16 (A/B frag)
typedef float f32x4 __attribute__((ext_vector_type(4)));   // C/D frag

#define MFMA(a, b, c) __builtin_amdgcn_mfma_f32_16x16x32_bf16((a), (b), (c), 0, 0, 0)

__device__ __forceinline__ unsigned short f2bf(float x) {
  union { float f; unsigned u; } v; v.f = x;
  unsigned r = v.u + 0x7fffu + ((v.u >> 16) & 1u);  // RNE
  return (unsigned short)(r >> 16);
}
__device__ __forceinline__ float bf2f(unsigned short h) {
  union { unsigned u; float f; } v; v.u = ((unsigned)h) << 16;
  return v.f;
}

__device__ __forceinline__ void gll16(const void* g, void* l) {
  __builtin_amdgcn_global_load_lds(
      (const __attribute__((address_space(1))) unsigned*)g,
      (__attribute__((address_space(3))) unsigned*)l, 16, 0, 0);
}

// ---------------- graph prep ----------------

__global__ void k_count2(const int* __restrict__ d1, const int* __restrict__ d2,
                         int* __restrict__ i1, int* __restrict__ i2) {
  int t = blockIdx.x * 256 + threadIdx.x;
  const int* d = blockIdx.y ? d2 : d1;
  int* ii = blockIdx.y ? i2 : i1;
  if (t < NE) atomicAdd(&ii[d[t]], 1);
}

__global__ void k_scan2(const int* __restrict__ ideg1, int* __restrict__ off1,
                        int* __restrict__ cur1, float* __restrict__ dinv1,
                        const int* __restrict__ ideg2, int* __restrict__ off2,
                        int* __restrict__ cur2, float* __restrict__ dinv2) {
  const int* indeg = blockIdx.x ? ideg2 : ideg1;
  int* off = blockIdx.x ? off2 : off1;
  int* cur = blockIdx.x ? cur2 : cur1;
  float* dinv = blockIdx.x ? dinv2 : dinv1;
  __shared__ int sh[1024];
  __shared__ int carry;
  int t = threadIdx.x;
  if (t == 0) carry = 0;
  __syncthreads();
  for (int base = 0; base < NN; base += 1024) {
    int v = indeg[base + t];
    sh[t] = v;
    __syncthreads();
    for (int s = 1; s < 1024; s <<= 1) {
      int add = (t >= s) ? sh[t - s] : 0;
      __syncthreads();
      sh[t] += add;
      __syncthreads();
    }
    int excl = carry + sh[t] - v;
    off[base + t] = excl;
    cur[base + t] = excl;
    dinv[base + t] = 1.0f / sqrtf((float)(v + 1));  // +1 self loop
    __syncthreads();
    if (t == 1023) carry += sh[t];
    __syncthreads();
  }
  if (t == 0) off[NN] = carry;
}

__global__ void k_fill2(const int* __restrict__ s1, const int* __restrict__ d1,
                        int* __restrict__ c1, int* __restrict__ l1,
                        const int* __restrict__ s2, const int* __restrict__ d2,
                        int* __restrict__ c2, int* __restrict__ l2) {
  int t = blockIdx.x * 256 + threadIdx.x;
  const int* src = blockIdx.y ? s2 : s1;
  const int* dst = blockIdx.y ? d2 : d1;
  int* cur = blockIdx.y ? c2 : c1;
  int* out = blockIdx.y ? l2 : l1;
  if (t < NE) {
    int d = dst[t];
    int slot = atomicAdd(&cur[d], 1);
    out[slot] = src[t];
  }
}

// ---------------- weight transpose + split (all 10 matrices, one launch) ----------------

__global__ void k_split_w(const float* W11, const float* W21, const float* W12,
                          const float* W22, const float* q1, const float* k1,
                          const float* v1, const float* q2, const float* k2,
                          const float* v2, short* __restrict__ whi,
                          short* __restrict__ wlo) {
  int y = blockIdx.y;
  const float* src; int R, C, base;
  if (y == 0)      { src = W11; R = 128; C = 256; base = 0; }
  else if (y == 1) { src = W21; R = 128; C = 256; base = 32768; }
  else if (y == 2) { src = W12; R = 256; C = 64;  base = 65536; }
  else if (y == 3) { src = W22; R = 256; C = 64;  base = 81920; }
  else if (y == 4) { src = q1;  R = 64;  C = 64;  base = 98304; }
  else if (y == 5) { src = k1;  R = 64;  C = 64;  base = 102400; }
  else if (y == 6) { src = v1;  R = 64;  C = 64;  base = 106496; }
  else if (y == 7) { src = q2;  R = 64;  C = 64;  base = 110592; }
  else if (y == 8) { src = k2;  R = 64;  C = 64;  base = 114688; }
  else             { src = v2;  R = 64;  C = 64;  base = 118784; }
  int idx = blockIdx.x * 256 + threadIdx.x;
  if (idx >= R * C) return;
  int r = idx / C, c = idx % C;
  float x = src[idx];
  unsigned short h = f2bf(x);
  whi[base + c * R + r] = (short)h;
  wlo[base + c * R + r] = (short)f2bf(x - bf2f(h));
}

// ---------------- layer-1 aggregation on raw x (D=128), wave per node ----------------

__global__ __launch_bounds__(256) void k_agg1(const float* __restrict__ x,
                                              const int* __restrict__ off,
                                              const int* __restrict__ srcl,
                                              const float* __restrict__ dinv,
                                              short* __restrict__ ahi,
                                              short* __restrict__ alo) {
  int wave = threadIdx.x >> 6, lane = threadIdx.x & 63;
  int node = blockIdx.x * 4 + wave;
  float dn = dinv[node];
  const float2* xr = (const float2*)x;
  float ax, ay;
  { float2 v = xr[(size_t)node * 64 + lane]; ax = dn * v.x; ay = dn * v.y; }
  int p = off[node], e = off[node + 1];
  for (; p + 3 < e; p += 4) {
    int s0 = srcl[p], s1 = srcl[p + 1], s2 = srcl[p + 2], s3 = srcl[p + 3];
    float w0 = dinv[s0], w1 = dinv[s1], w2 = dinv[s2], w3 = dinv[s3];
    float2 v0 = xr[(size_t)s0 * 64 + lane], v1 = xr[(size_t)s1 * 64 + lane];
    float2 v2 = xr[(size_t)s2 * 64 + lane], v3 = xr[(size_t)s3 * 64 + lane];
    ax += w0 * v0.x + w1 * v1.x + w2 * v2.x + w3 * v3.x;
    ay += w0 * v0.y + w1 * v1.y + w2 * v2.y + w3 * v3.y;
  }
  for (; p < e; ++p) {
    int s = srcl[p];
    float w = dinv[s];
    float2 v = xr[(size_t)s * 64 + lane];
    ax += w * v.x; ay += w * v.y;
  }
  float ox = dn * ax, oy = dn * ay;
  unsigned short hx = f2bf(ox), hy = f2bf(oy);
  int o = node * 128 + lane * 2;
  *(short2*)(ahi + o) = make_short2((short)hx, (short)hy);
  *(short2*)(alo + o) = make_short2((short)f2bf(ox - bf2f(hx)),
                                    (short)f2bf(oy - bf2f(hy)));
}

// ---------------- layer-2 aggregation (D=64) + bias, wave per node ----------------

__global__ __launch_bounds__(256) void k_agg2(const float* __restrict__ t,
                                              const int* __restrict__ off,
                                              const int* __restrict__ srcl,
                                              const float* __restrict__ dinv,
                                              const float* __restrict__ bias,
                                              short* __restrict__ ghi,
                                              short* __restrict__ glo) {
  int wave = threadIdx.x >> 6, lane = threadIdx.x & 63;
  int node = blockIdx.x * 4 + wave;
  float dn = dinv[node];
  float acc = dn * t[(size_t)node * 64 + lane];
  int p = off[node], e = off[node + 1];
  for (; p + 3 < e; p += 4) {
    int s0 = srcl[p], s1 = srcl[p + 1], s2 = srcl[p + 2], s3 = srcl[p + 3];
    float w0 = dinv[s0], w1 = dinv[s1], w2 = dinv[s2], w3 = dinv[s3];
    acc += w0 * t[(size_t)s0 * 64 + lane] + w1 * t[(size_t)s1 * 64 + lane] +
           w2 * t[(size_t)s2 * 64 + lane] + w3 * t[(size_t)s3 * 64 + lane];
  }
  for (; p < e; ++p) {
    int s = srcl[p];
    acc += dinv[s] * t[(size_t)s * 64 + lane];
  }
  float o = dn * acc + bias[lane];
  unsigned short h = f2bf(o);
  ghi[(size_t)node * 64 + lane] = (short)h;
  glo[(size_t)node * 64 + lane] = (short)f2bf(o - bf2f(h));
}

// ---------------- generic MFMA bf16x3 GEMM: C[Mx NTOT] = A[MxK] @ Bt[NTOT x K]^T ----------------
// 1 wave per block; wave tile = 16 rows x 64 cols.

template <int K, int NTOT, bool BIAS, bool RELU, bool OUTHL>
__global__ __launch_bounds__(64) void k_gemm_mfma(
    const short* __restrict__ Ahi, const short* __restrict__ Alo,
    const short* __restrict__ Bthi, const short* __restrict__ Btlo,
    const float* __restrict__ bias, short* __restrict__ Chi,
    short* __restrict__ Clo, float* __restrict__ Cf) {
  constexpr int KS = K / 32;
  int lane = threadIdx.x;
  int lo16 = lane & 15, hi4 = lane >> 4;
  int r0 = blockIdx.x * 16;
  int c0 = blockIdx.y * 64;
  bfrag ah[KS], al[KS];
  const char* abh = (const char*)Ahi + ((size_t)(r0 + lo16) * K + hi4 * 8) * 2;
  const char* abl = (const char*)Alo + ((size_t)(r0 + lo16) * K + hi4 * 8) * 2;
#pragma unroll
  for (int ks = 0; ks < KS; ++ks) {
    ah[ks] = *(const bfrag*)(abh + ks * 64);
    al[ks] = *(const bfrag*)(abl + ks * 64);
  }
  f32x4 z = {0.f, 0.f, 0.f, 0.f};
  f32x4 acc[4] = {z, z, z, z};
#pragma unroll
  for (int c = 0; c < 4; ++c) {
    const char* bbh = (const char*)Bthi + ((size_t)(c0 + c * 16 + lo16) * K + hi4 * 8) * 2;
    const char* bbl = (const char*)Btlo + ((size_t)(c0 + c * 16 + lo16) * K + hi4 * 8) * 2;
#pragma unroll
    for (int ks = 0; ks < KS; ++ks) {
      bfrag bh = *(const bfrag*)(bbh + ks * 64);
      bfrag bl = *(const bfrag*)(bbl + ks * 64);
      acc[c] = MFMA(ah[ks], bh, acc[c]);
      acc[c] = MFMA(ah[ks], bl, acc[c]);
      acc[c] = MFMA(al[ks], bh, acc[c]);
    }
  }
#pragma unroll
  for (int c = 0; c < 4; ++c) {
    int col = c0 + c * 16 + lo16;
    float bv = BIAS ? bias[col] : 0.f;
#pragma unroll
    for (int r = 0; r < 4; ++r) {
      int row = r0 + hi4 * 4 + r;
      float v = acc[c][r] + bv;
      if (RELU) v = fmaxf(v, 0.f);
      if (OUTHL) {
        unsigned short h = f2bf(v);
        Chi[(size_t)row * NTOT + col] = (short)h;
        Clo[(size_t)row * NTOT + col] = (short)f2bf(v - bf2f(h));
      } else {
        Cf[(size_t)row * NTOT + col] = v;
      }
    }
  }
}

// ---------------- QKV projections in one launch (grid.y selects Q/K/V) ----------------

__global__ __launch_bounds__(64) void k_qkv(
    const short* __restrict__ Aqhi, const short* __restrict__ Aqlo,
    const short* __restrict__ Akhi, const short* __restrict__ Aklo,
    const short* __restrict__ Avhi, const short* __restrict__ Avlo,
    const short* __restrict__ whi, const short* __restrict__ wlo,
    int bq, int bk, int bv,
    short* __restrict__ Qhi, short* __restrict__ Qlo,
    short* __restrict__ Khi, short* __restrict__ Klo, float* __restrict__ Vf) {
  int y = blockIdx.y;
  const short *Ah, *Al;
  int boff;
  if (y == 0)      { Ah = Aqhi; Al = Aqlo; boff = bq; }
  else if (y == 1) { Ah = Akhi; Al = Aklo; boff = bk; }
  else             { Ah = Avhi; Al = Avlo; boff = bv; }
  const short* Bh = whi + boff;
  const short* Bl = wlo + boff;
  int lane = threadIdx.x;
  int lo16 = lane & 15, hi4 = lane >> 4;
  int r0 = blockIdx.x * 16;
  bfrag ah0, ah1, al0, al1;
  {
    const char* a = (const char*)(Ah + (size_t)(r0 + lo16) * 64 + hi4 * 8);
    const char* b = (const char*)(Al + (size_t)(r0 + lo16) * 64 + hi4 * 8);
    ah0 = *(const bfrag*)a; ah1 = *(const bfrag*)(a + 64);
    al0 = *(const bfrag*)b; al1 = *(const bfrag*)(b + 64);
  }
  f32x4 z = {0.f, 0.f, 0.f, 0.f};
  f32x4 acc[4] = {z, z, z, z};
#pragma unroll
  for (int c = 0; c < 4; ++c) {
    const char* bbh = (const char*)(Bh + (size_t)(c * 16 + lo16) * 64 + hi4 * 8);
    const char* bbl = (const char*)(Bl + (size_t)(c * 16 + lo16) * 64 + hi4 * 8);
    bfrag bh0 = *(const bfrag*)bbh, bh1 = *(const bfrag*)(bbh + 64);
    bfrag bl0 = *(const bfrag*)bbl, bl1 = *(const bfrag*)(bbl + 64);
    acc[c] = MFMA(ah0, bh0, acc[c]);
    acc[c] = MFMA(ah1, bh1, acc[c]);
    acc[c] = MFMA(ah0, bl0, acc[c]);
    acc[c] = MFMA(ah1, bl1, acc[c]);
    acc[c] = MFMA(al0, bh0, acc[c]);
    acc[c] = MFMA(al1, bh1, acc[c]);
  }
#pragma unroll
  for (int c = 0; c < 4; ++c) {
    int col = c * 16 + lo16;
#pragma unroll
    for (int r = 0; r < 4; ++r) {
      int row = r0 + hi4 * 4 + r;
      float v = acc[c][r];
      if (y == 2) {
        Vf[(size_t)row * 64 + col] = v;
      } else {
        unsigned short h = f2bf(v);
        short* oh = (y == 0) ? Qhi : Khi;
        short* ol = (y == 0) ? Qlo : Klo;
        oh[(size_t)row * 64 + col] = (short)h;
        ol[(size_t)row * 64 + col] = (short)f2bf(v - bf2f(h));
      }
    }
  }
}

// V (NN x 64 f32) -> Vt hi/lo (64 x NN bf16)
__global__ __launch_bounds__(256) void k_split_tr(const float* __restrict__ V,
                                                  short* __restrict__ Vthi,
                                                  short* __restrict__ Vtlo) {
  __shared__ float tile[64][65];
  int n0 = blockIdx.x * 64;
  int c = threadIdx.x & 63;
  int rb = threadIdx.x >> 6;
  for (int r = rb; r < 64; r += 4) tile[r][c] = V[(size_t)(n0 + r) * 64 + c];
  __syncthreads();
  for (int r = rb; r < 64; r += 4) {  // r = d index
    float x = tile[c][r];
    unsigned short h = f2bf(x);
    Vthi[(size_t)r * NN + n0 + c] = (short)h;
    Vtlo[(size_t)r * NN + n0 + c] = (short)f2bf(x - bf2f(h));
  }
}

// ---------------- MFMA flash attention, LDS-staged K/V (2-phase double buffer) ----------------
// block = 4 waves x 16 Q rows; grid = (NN/64, NCH). K tile 32x64 hl, Vt tile 64x32 hl.

__global__ __launch_bounds__(256) void k_attn_v3(
    const short* __restrict__ Qhi, const short* __restrict__ Qlo,
    const short* __restrict__ Khi_g, const short* __restrict__ Klo_g,
    const short* __restrict__ Vthi_g, const short* __restrict__ Vtlo_g,
    float* __restrict__ Opart, float* __restrict__ mpart, float* __restrict__ lpart) {
  __shared__ short skh[2][32 * 64], skl[2][32 * 64];
  __shared__ short svh[2][64 * 32], svl[2][64 * 32];
  __shared__ short plds[4][16 * 40];
  const int tid = threadIdx.x;
  const int wave = tid >> 6, lane = tid & 63;
  const int lo16 = lane & 15, hi4 = lane >> 4;
  const int q0 = blockIdx.x * 64 + wave * 16;
  const int j0 = blockIdx.y * (NN / NCH);
  short* myp = plds[wave];

  // staging geometry: K tile rows 0..31 (128B rows, swz key row&7);
  // Vt tile rows 0..63 = d (64B rows, swz key (row>>1)&3)
  const int krow = wave * 8 + (lane >> 3);
  const int kcbs = ((lane & 7) * 16) ^ ((krow & 7) << 4);
  const int vrow = wave * 16 + (lane >> 2);
  const int vcbs = ((lane & 3) * 16) ^ (((vrow >> 1) & 3) << 4);
  const char* gkh = (const char*)Khi_g + (size_t)(j0 + krow) * 128 + kcbs;
  const char* gkl = (const char*)Klo_g + (size_t)(j0 + krow) * 128 + kcbs;
  const char* gvh = (const char*)Vthi_g + (size_t)vrow * (NN * 2) + (size_t)j0 * 2 + vcbs;
  const char* gvl = (const char*)Vtlo_g + (size_t)vrow * (NN * 2) + (size_t)j0 * 2 + vcbs;

#define STAGE(buf, s)                                             \
  do {                                                            \
    gll16(gkh + (size_t)(s) * 4096, (char*)skh[buf] + wave * 1024); \
    gll16(gkl + (size_t)(s) * 4096, (char*)skl[buf] + wave * 1024); \
    gll16(gvh + (s) * 64, (char*)svh[buf] + wave * 1024);           \
    gll16(gvl + (s) * 64, (char*)svl[buf] + wave * 1024);           \
  } while (0)

  // Q fragments (registers, whole sweep)
  const bfrag* qph = (const bfrag*)(Qhi + (size_t)(q0 + lo16) * 64 + hi4 * 8);
  const bfrag* qpl = (const bfrag*)(Qlo + (size_t)(q0 + lo16) * 64 + hi4 * 8);
  bfrag qh0 = qph[0], qh1 = qph[4];
  bfrag ql0 = qpl[0], ql1 = qpl[4];

  f32x4 z = {0.f, 0.f, 0.f, 0.f};
  f32x4 oacc[4] = {z, z, z, z};
  float mrun[4] = {-1e30f, -1e30f, -1e30f, -1e30f};
  float lsum[4] = {0.f, 0.f, 0.f, 0.f};

  STAGE(0, 0);
  __syncthreads();

  for (int s = 0; s < NS; ++s) {
    const int buf = s & 1;
    if (s + 1 < NS) STAGE(buf ^ 1, s + 1);
    const char* kh = (const char*)skh[buf];
    const char* kl = (const char*)skl[buf];
    // ---- scores ----
    f32x4 sa[2];
#pragma unroll
    for (int t = 0; t < 2; ++t) {
      int jr = 16 * t + lo16;
      int sw = (jr & 7) << 4;
      const char* rowh = kh + jr * 128;
      const char* rowl = kl + jr * 128;
      bfrag kh0 = *(const bfrag*)(rowh + ((hi4 * 16) ^ sw));
      bfrag kh1 = *(const bfrag*)(rowh + ((64 + hi4 * 16) ^ sw));
      bfrag kl0 = *(const bfrag*)(rowl + ((hi4 * 16) ^ sw));
      bfrag kl1 = *(const bfrag*)(rowl + ((64 + hi4 * 16) ^ sw));
      f32x4 acc = z;
      acc = MFMA(qh0, kh0, acc);
      acc = MFMA(qh1, kh1, acc);
      acc = MFMA(qh0, kl0, acc);
      acc = MFMA(qh1, kl1, acc);
      acc = MFMA(ql0, kh0, acc);
      acc = MFMA(ql1, kh1, acc);
      sa[t] = acc;
    }
    // leaky_relu(0.01)
#pragma unroll
    for (int t = 0; t < 2; ++t)
#pragma unroll
      for (int r = 0; r < 4; ++r) {
        float v = sa[t][r];
        sa[t][r] = fmaxf(v, 0.01f * v);
      }
    // row max over 32 cols
    float pm[4];
#pragma unroll
    for (int r = 0; r < 4; ++r) pm[r] = fmaxf(sa[0][r], sa[1][r]);
#pragma unroll
    for (int mask = 1; mask <= 8; mask <<= 1)
#pragma unroll
      for (int r = 0; r < 4; ++r) pm[r] = fmaxf(pm[r], __shfl_xor(pm[r], mask));
    // lazy rescale (defer-max, THR=4)
    bool rb = false;
#pragma unroll
    for (int r = 0; r < 4; ++r) rb |= (pm[r] > mrun[r] + 4.f);
    if (__any(rb)) {
#pragma unroll
      for (int r = 0; r < 4; ++r) {
        float nm = (pm[r] > mrun[r] + 4.f) ? pm[r] : mrun[r];
        float c_ = __expf(mrun[r] - nm);
        lsum[r] *= c_;
#pragma unroll
        for (int c = 0; c < 4; ++c) oacc[c][r] *= c_;
        mrun[r] = nm;
      }
    }
    // p = exp(s - m)
    float p0[4], p1[4];
#pragma unroll
    for (int r = 0; r < 4; ++r) {
      p0[r] = __expf(sa[0][r] - mrun[r]);
      p1[r] = __expf(sa[1][r] - mrun[r]);
      lsum[r] += p0[r] + p1[r];
    }
    // P tile -> per-wave LDS, read back as A-frag
#pragma unroll
    for (int r = 0; r < 4; ++r) {
      int row = hi4 * 4 + r;
      myp[row * 40 + lo16] = (short)f2bf(p0[r]);
      myp[row * 40 + 16 + lo16] = (short)f2bf(p1[r]);
    }
    bfrag pa = *(const bfrag*)(myp + lo16 * 40 + hi4 * 8);
    // ---- PV ----
    const char* vh = (const char*)svh[buf];
    const char* vl = (const char*)svl[buf];
#pragma unroll
    for (int c = 0; c < 4; ++c) {
      int dv = 16 * c + lo16;
      int svw = ((dv >> 1) & 3) << 4;
      bfrag vhf = *(const bfrag*)(vh + dv * 64 + ((hi4 * 16) ^ svw));
      bfrag vlf = *(const bfrag*)(vl + dv * 64 + ((hi4 * 16) ^ svw));
      oacc[c] = MFMA(pa, vhf, oacc[c]);
      oacc[c] = MFMA(pa, vlf, oacc[c]);
    }
    __syncthreads();
  }
#undef STAGE
  // reduce row sums across the 16 column-lanes
#pragma unroll
  for (int mask = 1; mask <= 8; mask <<= 1)
#pragma unroll
    for (int r = 0; r < 4; ++r) lsum[r] += __shfl_xor(lsum[r], mask);
  // store partials
#pragma unroll
  for (int c = 0; c < 4; ++c)
#pragma unroll
    for (int r = 0; r < 4; ++r)
      Opart[((size_t)blockIdx.y * NN + q0 + hi4 * 4 + r) * 64 + 16 * c + lo16] = oacc[c][r];
  if (lo16 == 0) {
#pragma unroll
    for (int r = 0; r < 4; ++r) {
      mpart[blockIdx.y * NN + q0 + hi4 * 4 + r] = mrun[r];
      lpart[blockIdx.y * NN + q0 + hi4 * 4 + r] = lsum[r];
    }
  }
}

// combine partials -> o hi/lo bf16
__global__ void k_comb(const float* __restrict__ Opart,
                       const float* __restrict__ mpart,
                       const float* __restrict__ lpart,
                       short* __restrict__ Ohi, short* __restrict__ Olo) {
  int row = blockIdx.x * 4 + (threadIdx.x >> 6);
  int d = threadIdx.x & 63;
  float M = -1e30f;
  for (int i = 0; i < NCH; ++i) M = fmaxf(M, mpart[i * NN + row]);
  float L = 0.f, acc = 0.f;
  for (int i = 0; i < NCH; ++i) {
    float w = __expf(mpart[i * NN + row] - M);
    L += w * lpart[i * NN + row];
    acc += w * Opart[((size_t)i * NN + row) * 64 + d];
  }
  float o = acc / L;
  unsigned short h = f2bf(o);
  Ohi[(size_t)row * 64 + d] = (short)h;
  Olo[(size_t)row * 64 + d] = (short)f2bf(o - bf2f(h));
}

// ---------------- logits = o1 @ o2^T via bf16x3 MFMA, B-frag ping-pong prefetch ----------------

__global__ __launch_bounds__(256) void k_outer(const short* __restrict__ o1hi,
                                               const short* __restrict__ o1lo,
                                               const short* __restrict__ o2hi,
                                               const short* __restrict__ o2lo,
                                               float* __restrict__ out) {
  int wave = threadIdx.x >> 6, lane = threadIdx.x & 63;
  int lo16 = lane & 15, hi4 = lane >> 4;
  int i0 = blockIdx.x * 64 + wave * 16;
  const bfrag* aph = (const bfrag*)(o1hi + (size_t)(i0 + lo16) * 64 + hi4 * 8);
  const bfrag* apl = (const bfrag*)(o1lo + (size_t)(i0 + lo16) * 64 + hi4 * 8);
  bfrag ah0 = aph[0], ah1 = aph[4];
  bfrag al0 = apl[0], al1 = apl[4];
  f32x4 z = {0.f, 0.f, 0.f, 0.f};
  int jbase = blockIdx.y * (NN / 16);

#define LOADB(JV, BH0, BH1, BL0, BL1)                                        \
  do {                                                                       \
    const bfrag* bph = (const bfrag*)(o2hi + (size_t)((JV) + lo16) * 64 + hi4 * 8); \
    const bfrag* bpl = (const bfrag*)(o2lo + (size_t)((JV) + lo16) * 64 + hi4 * 8); \
    BH0 = bph[0]; BH1 = bph[4]; BL0 = bpl[0]; BL1 = bpl[4];                  \
  } while (0)

#define COMP(JV, BH0, BH1, BL0, BL1)                                  \
  do {                                                                \
    f32x4 acc = z;                                                    \
    acc = MFMA(ah0, BH0, acc);                                        \
    acc = MFMA(ah1, BH1, acc);                                        \
    acc = MFMA(ah0, BL0, acc);                                        \
    acc = MFMA(ah1, BL1, acc);                                        \
    acc = MFMA(al0, BH0, acc);                                        \
    acc = MFMA(al1, BH1, acc);                                        \
    _Pragma("unroll")                                                 \
    for (int r = 0; r < 4; ++r)                                       \
      out[(size_t)(i0 + hi4 * 4 + r) * NN + (JV) + lo16] = acc[r];    \
  } while (0)

  bfrag pah0, pah1, pal0, pal1, pbh0, pbh1, pbl0, pbl1;
  LOADB(jbase, pah0, pah1, pal0, pal1);
  for (int jt = 0; jt < NN / 16 / 16; jt += 2) {
    int ja = jbase + jt * 16;
    LOADB(ja + 16, pbh0, pbh1, pbl0, pbl1);
    COMP(ja, pah0, pah1, pal0, pal1);
    if (jt + 2 < NN / 16 / 16) LOADB(ja + 32, pah0, pah1, pal0, pal1);
    COMP(ja + 16, pbh0, pbh1, pbl0, pbl1);
  }
#undef LOADB
#undef COMP
}

// ---------------- launch ----------------

extern "C" void kernel_launch(void* const* d_in, const int* in_sizes, int n_in,
                              void* d_out, int out_size, void* d_ws, size_t ws_size,
                              hipStream_t stream) {
  const int* g1 = (const int*)d_in[0];
  const int* g2 = (const int*)d_in[1];
  const float* x1 = (const float*)d_in[2];
  const float* x2 = (const float*)d_in[3];
  const float* W11 = (const float*)d_in[4];
  const float* b11 = (const float*)d_in[5];
  const float* W12 = (const float*)d_in[6];
  const float* b12 = (const float*)d_in[7];
  const float* W21 = (const float*)d_in[8];
  const float* b21 = (const float*)d_in[9];
  const float* W22 = (const float*)d_in[10];
  const float* b22 = (const float*)d_in[11];
  const float* q1 = (const float*)d_in[12];
  const float* k1 = (const float*)d_in[13];
  const float* v1 = (const float*)d_in[14];
  const float* q2 = (const float*)d_in[15];
  const float* k2 = (const float*)d_in[16];
  const float* v2 = (const float*)d_in[17];

  // d_out (256 MB) is scratch for everything that dies before k_outer.
  char* ob = (char*)d_out;
  const size_t MB = 1u << 20;
  int* srcl1 = (int*)(ob + 0 * MB);
  int* srcl2 = (int*)(ob + 1 * MB);
  char* small = ob + 2 * MB;
  int* ideg1 = (int*)(small);                    // 32KB (+ideg2 adjacent: 1 memset)
  int* ideg2 = (int*)(small + (32u << 10));
  int* off1 = (int*)(small + (64u << 10));
  int* off2 = (int*)(small + (128u << 10));
  int* cur1 = (int*)(small + (192u << 10));
  int* cur2 = (int*)(small + (256u << 10));
  float* dinv1 = (float*)(small + (320u << 10));
  float* dinv2 = (float*)(small + (384u << 10));
  short* whi = (short*)(ob + 3 * MB);            // 240KB
  short* wlo = (short*)(ob + 3 * MB + (512u << 10));
  short* a1hi = (short*)(ob + 4 * MB);           // 2MB each
  short* a1lo = (short*)(ob + 6 * MB);
  short* a2hi = (short*)(ob + 8 * MB);
  short* a2lo = (short*)(ob + 10 * MB);
  short* h1hi = (short*)(ob + 12 * MB);          // 4MB each
  short* h1lo = (short*)(ob + 16 * MB);
  short* h2hi = (short*)(ob + 20 * MB);
  short* h2lo = (short*)(ob + 24 * MB);
  float* tbuf = (float*)(ob + 28 * MB);          // 2MB
  short* g1hi = (short*)(ob + 30 * MB);          // 1MB each
  short* g1lo = (short*)(ob + 31 * MB);
  short* g2hi = (short*)(ob + 32 * MB);
  short* g2lo = (short*)(ob + 33 * MB);
  short* Qhi = (short*)(ob + 34 * MB);
  short* Qlo = (short*)(ob + 35 * MB);
  short* Khi = (short*)(ob + 36 * MB);
  short* Klo = (short*)(ob + 37 * MB);
  float* Vf = (float*)(ob + 38 * MB);            // 2MB
  short* Vthi = (short*)(ob + 40 * MB);
  short* Vtlo = (short*)(ob + 41 * MB);
  float* Opart = (float*)(ob + 42 * MB);         // 16MB
  float* mpart = (float*)(ob + 58 * MB);
  float* lpart = (float*)(ob + 58 * MB + (256u << 10));
  // d_ws: persists into k_outer
  short* o1hi = (short*)d_ws;
  short* o1lo = (short*)((char*)d_ws + 1 * MB);
  short* o2hi = (short*)((char*)d_ws + 2 * MB);
  short* o2lo = (short*)((char*)d_ws + 3 * MB);

  hipMemsetAsync(ideg1, 0, 64u << 10, stream);  // covers ideg1+ideg2
  k_count2<<<dim3(1024, 2), 256, 0, stream>>>(g1 + NE, g2 + NE, ideg1, ideg2);
  k_scan2<<<2, 1024, 0, stream>>>(ideg1, off1, cur1, dinv1, ideg2, off2, cur2, dinv2);
  k_fill2<<<dim3(1024, 2), 256, 0, stream>>>(g1, g1 + NE, cur1, srcl1,
                                             g2, g2 + NE, cur2, srcl2);
  k_split_w<<<dim3(128, 10), 256, 0, stream>>>(W11, W21, W12, W22, q1, k1, v1,
                                               q2, k2, v2, whi, wlo);

  // GCN branch 1: h1 = relu((agg x1)@W11 + b11); g1 = agg(h1@W12) + b12
  k_agg1<<<2048, 256, 0, stream>>>(x1, off1, srcl1, dinv1, a1hi, a1lo);
  k_gemm_mfma<128, 256, true, true, true><<<dim3(512, 4), 64, 0, stream>>>(
      a1hi, a1lo, whi + 0, wlo + 0, b11, h1hi, h1lo, nullptr);
  k_gemm_mfma<256, 64, false, false, false><<<dim3(512, 1), 64, 0, stream>>>(
      h1hi, h1lo, whi + 65536, wlo + 65536, nullptr, nullptr, nullptr, tbuf);
  k_agg2<<<2048, 256, 0, stream>>>(tbuf, off1, srcl1, dinv1, b12, g1hi, g1lo);
  // GCN branch 2
  k_agg1<<<2048, 256, 0, stream>>>(x2, off2, srcl2, dinv2, a2hi, a2lo);
  k_gemm_mfma<128, 256, true, true, true><<<dim3(512, 4), 64, 0, stream>>>(
      a2hi, a2lo, whi + 32768, wlo + 32768, b21, h2hi, h2lo, nullptr);
  k_gemm_mfma<256, 64, false, false, false><<<dim3(512, 1), 64, 0, stream>>>(
      h2hi, h2lo, whi + 81920, wlo + 81920, nullptr, nullptr, nullptr, tbuf);
  k_agg2<<<2048, 256, 0, stream>>>(tbuf, off2, srcl2, dinv2, b22, g2hi, g2lo);

  // cross attention 1: Q=g1@q1, K=g2@k1, V=g1@v1 -> o1
  k_qkv<<<dim3(512, 3), 64, 0, stream>>>(g1hi, g1lo, g2hi, g2lo, g1hi, g1lo,
                                         whi, wlo, 98304, 102400, 106496,
                                         Qhi, Qlo, Khi, Klo, Vf);
  k_split_tr<<<128, 256, 0, stream>>>(Vf, Vthi, Vtlo);
  k_attn_v3<<<dim3(128, NCH), 256, 0, stream>>>(Qhi, Qlo, Khi, Klo, Vthi, Vtlo,
                                                Opart, mpart, lpart);
  k_comb<<<2048, 256, 0, stream>>>(Opart, mpart, lpart, o1hi, o1lo);

  // cross attention 2: Q=g2@q2, K=o1@k2, V=g2@v2 -> o2
  k_qkv<<<dim3(512, 3), 64, 0, stream>>>(g2hi, g2lo, o1hi, o1lo, g2hi, g2lo,
                                         whi, wlo, 110592, 114688, 118784,
                                         Qhi, Qlo, Khi, Klo, Vf);
  k_split_tr<<<128, 256, 0, stream>>>(Vf, Vthi, Vtlo);
  k_attn_v3<<<dim3(128, NCH), 256, 0, stream>>>(Qhi, Qlo, Khi, Klo, Vthi, Vtlo,
                                                Opart, mpart, lpart);
  k_comb<<<2048, 256, 0, stream>>>(Opart, mpart, lpart, o2hi, o2lo);

  // logits = o1 @ o2^T -> d_out (overwrites all scratch)
  k_outer<<<dim3(128, 16), 256, 0, stream>>>(o1hi, o1lo, o2hi, o2lo, (float*)d_out);

  (void)in_sizes; (void)n_in; (void)out_size; (void)ws_size;
}

// Round 4
// 718.942 us; speedup vs baseline: 4.1077x; 1.0638x over previous
//
#include <hip/hip_runtime.h>
#include <math.h>

static constexpr int NN = 8192;      // nodes
static constexpr int NE = 262144;    // edges
static constexpr int NCH = 8;        // K-chunks for flash partials
static constexpr int NS = (NN / NCH) / 32;  // 32 steps per chunk

typedef short bfrag __attribute__((ext_vector_type(8)));   // 8 bf16 (A/B frag)
typedef float f32x4 __attribute__((ext_vector_type(4)));   // C/D frag

#define MFMA(a, b, c) __builtin_amdgcn_mfma_f32_16x16x32_bf16((a), (b), (c), 0, 0, 0)

__device__ __forceinline__ unsigned short f2bf(float x) {
  union { float f; unsigned u; } v; v.f = x;
  unsigned r = v.u + 0x7fffu + ((v.u >> 16) & 1u);  // RNE
  return (unsigned short)(r >> 16);
}
__device__ __forceinline__ float bf2f(unsigned short h) {
  union { unsigned u; float f; } v; v.u = ((unsigned)h) << 16;
  return v.f;
}

__device__ __forceinline__ void gll16(const void* g, void* l) {
  __builtin_amdgcn_global_load_lds(
      (const __attribute__((address_space(1))) unsigned*)g,
      (__attribute__((address_space(3))) unsigned*)l, 16, 0, 0);
}

// ---------------- graph prep ----------------

__global__ void k_count2(const int* __restrict__ d1, const int* __restrict__ d2,
                         int* __restrict__ i1, int* __restrict__ i2) {
  int t = blockIdx.x * 256 + threadIdx.x;
  const int* d = blockIdx.y ? d2 : d1;
  int* ii = blockIdx.y ? i2 : i1;
  if (t < NE) atomicAdd(&ii[d[t]], 1);
}

__global__ void k_scan2(const int* __restrict__ ideg1, int* __restrict__ off1,
                        int* __restrict__ cur1, float* __restrict__ dinv1,
                        const int* __restrict__ ideg2, int* __restrict__ off2,
                        int* __restrict__ cur2, float* __restrict__ dinv2) {
  const int* indeg = blockIdx.x ? ideg2 : ideg1;
  int* off = blockIdx.x ? off2 : off1;
  int* cur = blockIdx.x ? cur2 : cur1;
  float* dinv = blockIdx.x ? dinv2 : dinv1;
  __shared__ int sh[1024];
  __shared__ int carry;
  int t = threadIdx.x;
  if (t == 0) carry = 0;
  __syncthreads();
  for (int base = 0; base < NN; base += 1024) {
    int v = indeg[base + t];
    sh[t] = v;
    __syncthreads();
    for (int s = 1; s < 1024; s <<= 1) {
      int add = (t >= s) ? sh[t - s] : 0;
      __syncthreads();
      sh[t] += add;
      __syncthreads();
    }
    int excl = carry + sh[t] - v;
    off[base + t] = excl;
    cur[base + t] = excl;
    dinv[base + t] = 1.0f / sqrtf((float)(v + 1));  // +1 self loop
    __syncthreads();
    if (t == 1023) carry += sh[t];
    __syncthreads();
  }
  if (t == 0) off[NN] = carry;
}

__global__ void k_fill2(const int* __restrict__ s1, const int* __restrict__ d1,
                        int* __restrict__ c1, int* __restrict__ l1,
                        const int* __restrict__ s2, const int* __restrict__ d2,
                        int* __restrict__ c2, int* __restrict__ l2) {
  int t = blockIdx.x * 256 + threadIdx.x;
  const int* src = blockIdx.y ? s2 : s1;
  const int* dst = blockIdx.y ? d2 : d1;
  int* cur = blockIdx.y ? c2 : c1;
  int* out = blockIdx.y ? l2 : l1;
  if (t < NE) {
    int d = dst[t];
    int slot = atomicAdd(&cur[d], 1);
    out[slot] = src[t];
  }
}

// ---------------- weight transpose + split (all 10 matrices, one launch) ----------------

__global__ void k_split_w(const float* W11, const float* W21, const float* W12,
                          const float* W22, const float* q1, const float* k1,
                          const float* v1, const float* q2, const float* k2,
                          const float* v2, short* __restrict__ whi,
                          short* __restrict__ wlo) {
  int y = blockIdx.y;
  const float* src; int R, C, base;
  if (y == 0)      { src = W11; R = 128; C = 256; base = 0; }
  else if (y == 1) { src = W21; R = 128; C = 256; base = 32768; }
  else if (y == 2) { src = W12; R = 256; C = 64;  base = 65536; }
  else if (y == 3) { src = W22; R = 256; C = 64;  base = 81920; }
  else if (y == 4) { src = q1;  R = 64;  C = 64;  base = 98304; }
  else if (y == 5) { src = k1;  R = 64;  C = 64;  base = 102400; }
  else if (y == 6) { src = v1;  R = 64;  C = 64;  base = 106496; }
  else if (y == 7) { src = q2;  R = 64;  C = 64;  base = 110592; }
  else if (y == 8) { src = k2;  R = 64;  C = 64;  base = 114688; }
  else             { src = v2;  R = 64;  C = 64;  base = 118784; }
  int idx = blockIdx.x * 256 + threadIdx.x;
  if (idx >= R * C) return;
  int r = idx / C, c = idx % C;
  float x = src[idx];
  unsigned short h = f2bf(x);
  whi[base + c * R + r] = (short)h;
  wlo[base + c * R + r] = (short)f2bf(x - bf2f(h));
}

// ---------------- layer-1 aggregation on raw x (D=128), wave per node, both branches ----------------

__global__ __launch_bounds__(256) void k_agg1d(
    const float* __restrict__ x1, const float* __restrict__ x2,
    const int* __restrict__ off1, const int* __restrict__ srcl1,
    const float* __restrict__ dinv1, const int* __restrict__ off2,
    const int* __restrict__ srcl2, const float* __restrict__ dinv2,
    short* __restrict__ a1hi, short* __restrict__ a1lo,
    short* __restrict__ a2hi, short* __restrict__ a2lo) {
  int br = blockIdx.y;
  const float* x = br ? x2 : x1;
  const int* off = br ? off2 : off1;
  const int* srcl = br ? srcl2 : srcl1;
  const float* dinv = br ? dinv2 : dinv1;
  short* ahi = br ? a2hi : a1hi;
  short* alo = br ? a2lo : a1lo;
  int wave = threadIdx.x >> 6, lane = threadIdx.x & 63;
  int node = blockIdx.x * 4 + wave;
  float dn = dinv[node];
  const float2* xr = (const float2*)x;
  float ax, ay;
  { float2 v = xr[(size_t)node * 64 + lane]; ax = dn * v.x; ay = dn * v.y; }
  int p = off[node], e = off[node + 1];
  for (; p + 3 < e; p += 4) {
    int s0 = srcl[p], s1 = srcl[p + 1], s2 = srcl[p + 2], s3 = srcl[p + 3];
    float w0 = dinv[s0], w1 = dinv[s1], w2 = dinv[s2], w3 = dinv[s3];
    float2 v0 = xr[(size_t)s0 * 64 + lane], v1 = xr[(size_t)s1 * 64 + lane];
    float2 v2 = xr[(size_t)s2 * 64 + lane], v3 = xr[(size_t)s3 * 64 + lane];
    ax += w0 * v0.x + w1 * v1.x + w2 * v2.x + w3 * v3.x;
    ay += w0 * v0.y + w1 * v1.y + w2 * v2.y + w3 * v3.y;
  }
  for (; p < e; ++p) {
    int s = srcl[p];
    float w = dinv[s];
    float2 v = xr[(size_t)s * 64 + lane];
    ax += w * v.x; ay += w * v.y;
  }
  float ox = dn * ax, oy = dn * ay;
  unsigned short hx = f2bf(ox), hy = f2bf(oy);
  int o = node * 128 + lane * 2;
  *(short2*)(ahi + o) = make_short2((short)hx, (short)hy);
  *(short2*)(alo + o) = make_short2((short)f2bf(ox - bf2f(hx)),
                                    (short)f2bf(oy - bf2f(hy)));
}

// ---------------- layer-2 aggregation (D=64) + bias, wave per node, both branches ----------------

__global__ __launch_bounds__(256) void k_agg2d(
    const float* __restrict__ t1, const float* __restrict__ t2,
    const int* __restrict__ off1, const int* __restrict__ srcl1,
    const float* __restrict__ dinv1, const int* __restrict__ off2,
    const int* __restrict__ srcl2, const float* __restrict__ dinv2,
    const float* __restrict__ b12, const float* __restrict__ b22,
    short* __restrict__ g1hi, short* __restrict__ g1lo,
    short* __restrict__ g2hi, short* __restrict__ g2lo) {
  int br = blockIdx.y;
  const float* t = br ? t2 : t1;
  const int* off = br ? off2 : off1;
  const int* srcl = br ? srcl2 : srcl1;
  const float* dinv = br ? dinv2 : dinv1;
  const float* bias = br ? b22 : b12;
  short* ghi = br ? g2hi : g1hi;
  short* glo = br ? g2lo : g1lo;
  int wave = threadIdx.x >> 6, lane = threadIdx.x & 63;
  int node = blockIdx.x * 4 + wave;
  float dn = dinv[node];
  float acc = dn * t[(size_t)node * 64 + lane];
  int p = off[node], e = off[node + 1];
  for (; p + 3 < e; p += 4) {
    int s0 = srcl[p], s1 = srcl[p + 1], s2 = srcl[p + 2], s3 = srcl[p + 3];
    float w0 = dinv[s0], w1 = dinv[s1], w2 = dinv[s2], w3 = dinv[s3];
    acc += w0 * t[(size_t)s0 * 64 + lane] + w1 * t[(size_t)s1 * 64 + lane] +
           w2 * t[(size_t)s2 * 64 + lane] + w3 * t[(size_t)s3 * 64 + lane];
  }
  for (; p < e; ++p) {
    int s = srcl[p];
    acc += dinv[s] * t[(size_t)s * 64 + lane];
  }
  float o = dn * acc + bias[lane];
  unsigned short h = f2bf(o);
  ghi[(size_t)node * 64 + lane] = (short)h;
  glo[(size_t)node * 64 + lane] = (short)f2bf(o - bf2f(h));
}

// ---------------- GCN layer-1 GEMM (K=128, N=256, bias+relu, hl out), both branches ----------------

__global__ __launch_bounds__(64) void k_gemmL1(
    const short* __restrict__ a1hi, const short* __restrict__ a1lo,
    const short* __restrict__ a2hi, const short* __restrict__ a2lo,
    const short* __restrict__ whi, const short* __restrict__ wlo,
    const float* __restrict__ b11, const float* __restrict__ b21,
    short* __restrict__ h1hi, short* __restrict__ h1lo,
    short* __restrict__ h2hi, short* __restrict__ h2lo) {
  int br = blockIdx.z;
  const short* Ahi = br ? a2hi : a1hi;
  const short* Alo = br ? a2lo : a1lo;
  const short* Bh = whi + (br ? 32768 : 0);
  const short* Bl = wlo + (br ? 32768 : 0);
  const float* bias = br ? b21 : b11;
  short* Chi = br ? h2hi : h1hi;
  short* Clo = br ? h2lo : h1lo;
  int lane = threadIdx.x;
  int lo16 = lane & 15, hi4 = lane >> 4;
  int r0 = blockIdx.x * 16;
  int c0 = blockIdx.y * 64;
  bfrag ah[4], al[4];
  const char* abh = (const char*)Ahi + ((size_t)(r0 + lo16) * 128 + hi4 * 8) * 2;
  const char* abl = (const char*)Alo + ((size_t)(r0 + lo16) * 128 + hi4 * 8) * 2;
#pragma unroll
  for (int ks = 0; ks < 4; ++ks) {
    ah[ks] = *(const bfrag*)(abh + ks * 64);
    al[ks] = *(const bfrag*)(abl + ks * 64);
  }
  f32x4 z = {0.f, 0.f, 0.f, 0.f};
  f32x4 acc[4] = {z, z, z, z};
#pragma unroll
  for (int c = 0; c < 4; ++c) {
    const char* bbh = (const char*)Bh + ((size_t)(c0 + c * 16 + lo16) * 128 + hi4 * 8) * 2;
    const char* bbl = (const char*)Bl + ((size_t)(c0 + c * 16 + lo16) * 128 + hi4 * 8) * 2;
#pragma unroll
    for (int ks = 0; ks < 4; ++ks) {
      bfrag bh = *(const bfrag*)(bbh + ks * 64);
      bfrag bl = *(const bfrag*)(bbl + ks * 64);
      acc[c] = MFMA(ah[ks], bh, acc[c]);
      acc[c] = MFMA(ah[ks], bl, acc[c]);
      acc[c] = MFMA(al[ks], bh, acc[c]);
    }
  }
#pragma unroll
  for (int c = 0; c < 4; ++c) {
    int col = c0 + c * 16 + lo16;
    float bv = bias[col];
#pragma unroll
    for (int r = 0; r < 4; ++r) {
      int row = r0 + hi4 * 4 + r;
      float v = fmaxf(acc[c][r] + bv, 0.f);
      unsigned short h = f2bf(v);
      Chi[(size_t)row * 256 + col] = (short)h;
      Clo[(size_t)row * 256 + col] = (short)f2bf(v - bf2f(h));
    }
  }
}

// ---------------- GCN layer-2 GEMM (K=256, N=64, f32 out), both branches ----------------

__global__ __launch_bounds__(64) void k_gemmL2(
    const short* __restrict__ h1hi, const short* __restrict__ h1lo,
    const short* __restrict__ h2hi, const short* __restrict__ h2lo,
    const short* __restrict__ whi, const short* __restrict__ wlo,
    float* __restrict__ t1, float* __restrict__ t2) {
  int br = blockIdx.y;
  const short* Ahi = br ? h2hi : h1hi;
  const short* Alo = br ? h2lo : h1lo;
  const short* Bh = whi + (br ? 81920 : 65536);
  const short* Bl = wlo + (br ? 81920 : 65536);
  float* Cf = br ? t2 : t1;
  int lane = threadIdx.x;
  int lo16 = lane & 15, hi4 = lane >> 4;
  int r0 = blockIdx.x * 16;
  bfrag ah[8], al[8];
  const char* abh = (const char*)Ahi + ((size_t)(r0 + lo16) * 256 + hi4 * 8) * 2;
  const char* abl = (const char*)Alo + ((size_t)(r0 + lo16) * 256 + hi4 * 8) * 2;
#pragma unroll
  for (int ks = 0; ks < 8; ++ks) {
    ah[ks] = *(const bfrag*)(abh + ks * 64);
    al[ks] = *(const bfrag*)(abl + ks * 64);
  }
  f32x4 z = {0.f, 0.f, 0.f, 0.f};
  f32x4 acc[4] = {z, z, z, z};
#pragma unroll
  for (int c = 0; c < 4; ++c) {
    const char* bbh = (const char*)Bh + ((size_t)(c * 16 + lo16) * 256 + hi4 * 8) * 2;
    const char* bbl = (const char*)Bl + ((size_t)(c * 16 + lo16) * 256 + hi4 * 8) * 2;
#pragma unroll
    for (int ks = 0; ks < 8; ++ks) {
      bfrag bh = *(const bfrag*)(bbh + ks * 64);
      bfrag bl = *(const bfrag*)(bbl + ks * 64);
      acc[c] = MFMA(ah[ks], bh, acc[c]);
      acc[c] = MFMA(ah[ks], bl, acc[c]);
      acc[c] = MFMA(al[ks], bh, acc[c]);
    }
  }
#pragma unroll
  for (int c = 0; c < 4; ++c) {
    int col = c * 16 + lo16;
#pragma unroll
    for (int r = 0; r < 4; ++r)
      Cf[(size_t)(r0 + hi4 * 4 + r) * 64 + col] = acc[c][r];
  }
}

// ---------------- QKV projections; V writes transposed hi/lo directly ----------------

__global__ __launch_bounds__(64) void k_qkv(
    const short* __restrict__ Aqhi, const short* __restrict__ Aqlo,
    const short* __restrict__ Akhi, const short* __restrict__ Aklo,
    const short* __restrict__ Avhi, const short* __restrict__ Avlo,
    const short* __restrict__ whi, const short* __restrict__ wlo,
    int bq, int bk, int bv,
    short* __restrict__ Qhi, short* __restrict__ Qlo,
    short* __restrict__ Khi, short* __restrict__ Klo,
    short* __restrict__ Vthi, short* __restrict__ Vtlo) {
  int y = blockIdx.y;
  const short *Ah, *Al;
  int boff;
  if (y == 0)      { Ah = Aqhi; Al = Aqlo; boff = bq; }
  else if (y == 1) { Ah = Akhi; Al = Aklo; boff = bk; }
  else             { Ah = Avhi; Al = Avlo; boff = bv; }
  const short* Bh = whi + boff;
  const short* Bl = wlo + boff;
  int lane = threadIdx.x;
  int lo16 = lane & 15, hi4 = lane >> 4;
  int r0 = blockIdx.x * 16;
  bfrag ah0, ah1, al0, al1;
  {
    const char* a = (const char*)(Ah + (size_t)(r0 + lo16) * 64 + hi4 * 8);
    const char* b = (const char*)(Al + (size_t)(r0 + lo16) * 64 + hi4 * 8);
    ah0 = *(const bfrag*)a; ah1 = *(const bfrag*)(a + 64);
    al0 = *(const bfrag*)b; al1 = *(const bfrag*)(b + 64);
  }
  f32x4 z = {0.f, 0.f, 0.f, 0.f};
  f32x4 acc[4] = {z, z, z, z};
#pragma unroll
  for (int c = 0; c < 4; ++c) {
    const char* bbh = (const char*)(Bh + (size_t)(c * 16 + lo16) * 64 + hi4 * 8);
    const char* bbl = (const char*)(Bl + (size_t)(c * 16 + lo16) * 64 + hi4 * 8);
    bfrag bh0 = *(const bfrag*)bbh, bh1 = *(const bfrag*)(bbh + 64);
    bfrag bl0 = *(const bfrag*)bbl, bl1 = *(const bfrag*)(bbl + 64);
    acc[c] = MFMA(ah0, bh0, acc[c]);
    acc[c] = MFMA(ah1, bh1, acc[c]);
    acc[c] = MFMA(ah0, bl0, acc[c]);
    acc[c] = MFMA(ah1, bl1, acc[c]);
    acc[c] = MFMA(al0, bh0, acc[c]);
    acc[c] = MFMA(al1, bh1, acc[c]);
  }
  if (y == 2) {
    // V: write transposed split directly. Lane owns rows r0+hi4*4..+3 of col.
#pragma unroll
    for (int c = 0; c < 4; ++c) {
      int col = c * 16 + lo16;
      short4 vh, vl;
      float v0 = acc[c][0], v1 = acc[c][1], v2 = acc[c][2], v3 = acc[c][3];
      unsigned short h0 = f2bf(v0), h1 = f2bf(v1), h2 = f2bf(v2), h3 = f2bf(v3);
      vh = make_short4((short)h0, (short)h1, (short)h2, (short)h3);
      vl = make_short4((short)f2bf(v0 - bf2f(h0)), (short)f2bf(v1 - bf2f(h1)),
                       (short)f2bf(v2 - bf2f(h2)), (short)f2bf(v3 - bf2f(h3)));
      size_t o = (size_t)col * NN + r0 + hi4 * 4;
      *(short4*)(Vthi + o) = vh;
      *(short4*)(Vtlo + o) = vl;
    }
  } else {
    short* oh = (y == 0) ? Qhi : Khi;
    short* ol = (y == 0) ? Qlo : Klo;
#pragma unroll
    for (int c = 0; c < 4; ++c) {
      int col = c * 16 + lo16;
#pragma unroll
      for (int r = 0; r < 4; ++r) {
        int row = r0 + hi4 * 4 + r;
        float v = acc[c][r];
        unsigned short h = f2bf(v);
        oh[(size_t)row * 64 + col] = (short)h;
        ol[(size_t)row * 64 + col] = (short)f2bf(v - bf2f(h));
      }
    }
  }
}

// ---------------- MFMA flash attention, LDS-staged K/V, 8 waves x 16 Q rows ----------------
// grid = (NN/128, NCH); block 512. K tile 32x64 hl, Vt tile 64x32 hl, double-buffered.

__global__ __launch_bounds__(512) void k_attn_v4(
    const short* __restrict__ Qhi, const short* __restrict__ Qlo,
    const short* __restrict__ Khi_g, const short* __restrict__ Klo_g,
    const short* __restrict__ Vthi_g, const short* __restrict__ Vtlo_g,
    float* __restrict__ Opart, float* __restrict__ mpart, float* __restrict__ lpart) {
  __shared__ short skh[2][32 * 64], skl[2][32 * 64];
  __shared__ short svh[2][64 * 32], svl[2][64 * 32];
  __shared__ short plds[8][16 * 40];
  const int tid = threadIdx.x;
  const int wave = tid >> 6, lane = tid & 63;
  const int lo16 = lane & 15, hi4 = lane >> 4;
  const int q0 = blockIdx.x * 128 + wave * 16;
  const int j0 = blockIdx.y * (NN / NCH);
  const int wv = wave & 3;
  short* myp = plds[wave];

  // staging: waves 0-3 stage K hi/lo; waves 4-7 stage Vt hi/lo
  const int krow = wv * 8 + (lane >> 3);
  const int kcbs = ((lane & 7) * 16) ^ ((krow & 7) << 4);
  const int vrow = wv * 16 + (lane >> 2);
  const int vcbs = ((lane & 3) * 16) ^ (((vrow >> 1) & 3) << 4);
  const char* gka = (const char*)Khi_g + (size_t)(j0 + krow) * 128 + kcbs;
  const char* gkb = (const char*)Klo_g + (size_t)(j0 + krow) * 128 + kcbs;
  const char* gva = (const char*)Vthi_g + (size_t)vrow * (NN * 2) + (size_t)j0 * 2 + vcbs;
  const char* gvb = (const char*)Vtlo_g + (size_t)vrow * (NN * 2) + (size_t)j0 * 2 + vcbs;

#define STAGE(buf, s)                                                \
  do {                                                               \
    if (wave < 4) {                                                  \
      gll16(gka + (size_t)(s) * 4096, (char*)skh[buf] + wv * 1024);  \
      gll16(gkb + (size_t)(s) * 4096, (char*)skl[buf] + wv * 1024);  \
    } else {                                                         \
      gll16(gva + (s) * 64, (char*)svh[buf] + wv * 1024);            \
      gll16(gvb + (s) * 64, (char*)svl[buf] + wv * 1024);            \
    }                                                                \
  } while (0)

  // Q fragments (registers, whole sweep)
  const bfrag* qph = (const bfrag*)(Qhi + (size_t)(q0 + lo16) * 64 + hi4 * 8);
  const bfrag* qpl = (const bfrag*)(Qlo + (size_t)(q0 + lo16) * 64 + hi4 * 8);
  bfrag qh0 = qph[0], qh1 = qph[4];
  bfrag ql0 = qpl[0], ql1 = qpl[4];

  f32x4 z = {0.f, 0.f, 0.f, 0.f};
  f32x4 oacc[4] = {z, z, z, z};
  float mrun[4] = {-1e30f, -1e30f, -1e30f, -1e30f};
  float lsum[4] = {0.f, 0.f, 0.f, 0.f};

  STAGE(0, 0);
  __syncthreads();

  for (int s = 0; s < NS; ++s) {
    const int buf = s & 1;
    if (s + 1 < NS) STAGE(buf ^ 1, s + 1);
    const char* kh = (const char*)skh[buf];
    const char* kl = (const char*)skl[buf];
    // ---- scores ----
    f32x4 sa[2];
#pragma unroll
    for (int t = 0; t < 2; ++t) {
      int jr = 16 * t + lo16;
      int sw = (jr & 7) << 4;
      const char* rowh = kh + jr * 128;
      const char* rowl = kl + jr * 128;
      bfrag kh0 = *(const bfrag*)(rowh + ((hi4 * 16) ^ sw));
      bfrag kh1 = *(const bfrag*)(rowh + ((64 + hi4 * 16) ^ sw));
      bfrag kl0 = *(const bfrag*)(rowl + ((hi4 * 16) ^ sw));
      bfrag kl1 = *(const bfrag*)(rowl + ((64 + hi4 * 16) ^ sw));
      f32x4 acc = z;
      acc = MFMA(qh0, kh0, acc);
      acc = MFMA(qh1, kh1, acc);
      acc = MFMA(qh0, kl0, acc);
      acc = MFMA(qh1, kl1, acc);
      acc = MFMA(ql0, kh0, acc);
      acc = MFMA(ql1, kh1, acc);
      sa[t] = acc;
    }
    // leaky_relu(0.01)
#pragma unroll
    for (int t = 0; t < 2; ++t)
#pragma unroll
      for (int r = 0; r < 4; ++r) {
        float v = sa[t][r];
        sa[t][r] = fmaxf(v, 0.01f * v);
      }
    // row max over 32 cols
    float pm[4];
#pragma unroll
    for (int r = 0; r < 4; ++r) pm[r] = fmaxf(sa[0][r], sa[1][r]);
#pragma unroll
    for (int mask = 1; mask <= 8; mask <<= 1)
#pragma unroll
      for (int r = 0; r < 4; ++r) pm[r] = fmaxf(pm[r], __shfl_xor(pm[r], mask));
    // lazy rescale (defer-max, THR=4)
    bool rb = false;
#pragma unroll
    for (int r = 0; r < 4; ++r) rb |= (pm[r] > mrun[r] + 4.f);
    if (__any(rb)) {
#pragma unroll
      for (int r = 0; r < 4; ++r) {
        float nm = (pm[r] > mrun[r] + 4.f) ? pm[r] : mrun[r];
        float c_ = __expf(mrun[r] - nm);
        lsum[r] *= c_;
#pragma unroll
        for (int c = 0; c < 4; ++c) oacc[c][r] *= c_;
        mrun[r] = nm;
      }
    }
    // p = exp(s - m)
    float p0[4], p1[4];
#pragma unroll
    for (int r = 0; r < 4; ++r) {
      p0[r] = __expf(sa[0][r] - mrun[r]);
      p1[r] = __expf(sa[1][r] - mrun[r]);
      lsum[r] += p0[r] + p1[r];
    }
    // P tile -> per-wave LDS, read back as A-frag
#pragma unroll
    for (int r = 0; r < 4; ++r) {
      int row = hi4 * 4 + r;
      myp[row * 40 + lo16] = (short)f2bf(p0[r]);
      myp[row * 40 + 16 + lo16] = (short)f2bf(p1[r]);
    }
    bfrag pa = *(const bfrag*)(myp + lo16 * 40 + hi4 * 8);
    // ---- PV ----
    const char* vh = (const char*)svh[buf];
    const char* vl = (const char*)svl[buf];
#pragma unroll
    for (int c = 0; c < 4; ++c) {
      int dv = 16 * c + lo16;
      int svw = ((dv >> 1) & 3) << 4;
      bfrag vhf = *(const bfrag*)(vh + dv * 64 + ((hi4 * 16) ^ svw));
      bfrag vlf = *(const bfrag*)(vl + dv * 64 + ((hi4 * 16) ^ svw));
      oacc[c] = MFMA(pa, vhf, oacc[c]);
      oacc[c] = MFMA(pa, vlf, oacc[c]);
    }
    __syncthreads();
  }
#undef STAGE
  // reduce row sums across the 16 column-lanes
#pragma unroll
  for (int mask = 1; mask <= 8; mask <<= 1)
#pragma unroll
    for (int r = 0; r < 4; ++r) lsum[r] += __shfl_xor(lsum[r], mask);
  // store partials
#pragma unroll
  for (int c = 0; c < 4; ++c)
#pragma unroll
    for (int r = 0; r < 4; ++r)
      Opart[((size_t)blockIdx.y * NN + q0 + hi4 * 4 + r) * 64 + 16 * c + lo16] = oacc[c][r];
  if (lo16 == 0) {
#pragma unroll
    for (int r = 0; r < 4; ++r) {
      mpart[blockIdx.y * NN + q0 + hi4 * 4 + r] = mrun[r];
      lpart[blockIdx.y * NN + q0 + hi4 * 4 + r] = lsum[r];
    }
  }
}

// combine partials -> o hi/lo bf16
__global__ void k_comb(const float* __restrict__ Opart,
                       const float* __restrict__ mpart,
                       const float* __restrict__ lpart,
                       short* __restrict__ Ohi, short* __restrict__ Olo) {
  int row = blockIdx.x * 4 + (threadIdx.x >> 6);
  int d = threadIdx.x & 63;
  float M = -1e30f;
  for (int i = 0; i < NCH; ++i) M = fmaxf(M, mpart[i * NN + row]);
  float L = 0.f, acc = 0.f;
  for (int i = 0; i < NCH; ++i) {
    float w = __expf(mpart[i * NN + row] - M);
    L += w * lpart[i * NN + row];
    acc += w * Opart[((size_t)i * NN + row) * 64 + d];
  }
  float o = acc / L;
  unsigned short h = f2bf(o);
  Ohi[(size_t)row * 64 + d] = (short)h;
  Olo[(size_t)row * 64 + d] = (short)f2bf(o - bf2f(h));
}

// ---------------- logits = o1 @ o2^T via bf16x3 MFMA, B-frag ping-pong prefetch ----------------

__global__ __launch_bounds__(256) void k_outer(const short* __restrict__ o1hi,
                                               const short* __restrict__ o1lo,
                                               const short* __restrict__ o2hi,
                                               const short* __restrict__ o2lo,
                                               float* __restrict__ out) {
  int wave = threadIdx.x >> 6, lane = threadIdx.x & 63;
  int lo16 = lane & 15, hi4 = lane >> 4;
  int i0 = blockIdx.x * 64 + wave * 16;
  const bfrag* aph = (const bfrag*)(o1hi + (size_t)(i0 + lo16) * 64 + hi4 * 8);
  const bfrag* apl = (const bfrag*)(o1lo + (size_t)(i0 + lo16) * 64 + hi4 * 8);
  bfrag ah0 = aph[0], ah1 = aph[4];
  bfrag al0 = apl[0], al1 = apl[4];
  f32x4 z = {0.f, 0.f, 0.f, 0.f};
  int jbase = blockIdx.y * (NN / 16);

#define LOADB(JV, BH0, BH1, BL0, BL1)                                        \
  do {                                                                       \
    const bfrag* bph = (const bfrag*)(o2hi + (size_t)((JV) + lo16) * 64 + hi4 * 8); \
    const bfrag* bpl = (const bfrag*)(o2lo + (size_t)((JV) + lo16) * 64 + hi4 * 8); \
    BH0 = bph[0]; BH1 = bph[4]; BL0 = bpl[0]; BL1 = bpl[4];                  \
  } while (0)

#define COMP(JV, BH0, BH1, BL0, BL1)                                  \
  do {                                                                \
    f32x4 acc = z;                                                    \
    acc = MFMA(ah0, BH0, acc);                                        \
    acc = MFMA(ah1, BH1, acc);                                        \
    acc = MFMA(ah0, BL0, acc);                                        \
    acc = MFMA(ah1, BL1, acc);                                        \
    acc = MFMA(al0, BH0, acc);                                        \
    acc = MFMA(al1, BH1, acc);                                        \
    _Pragma("unroll")                                                 \
    for (int r = 0; r < 4; ++r)                                       \
      out[(size_t)(i0 + hi4 * 4 + r) * NN + (JV) + lo16] = acc[r];    \
  } while (0)

  bfrag pah0, pah1, pal0, pal1, pbh0, pbh1, pbl0, pbl1;
  LOADB(jbase, pah0, pah1, pal0, pal1);
  for (int jt = 0; jt < NN / 16 / 16; jt += 2) {
    int ja = jbase + jt * 16;
    LOADB(ja + 16, pbh0, pbh1, pbl0, pbl1);
    COMP(ja, pah0, pah1, pal0, pal1);
    if (jt + 2 < NN / 16 / 16) LOADB(ja + 32, pah0, pah1, pal0, pal1);
    COMP(ja + 16, pbh0, pbh1, pbl0, pbl1);
  }
#undef LOADB
#undef COMP
}

// ---------------- launch ----------------

extern "C" void kernel_launch(void* const* d_in, const int* in_sizes, int n_in,
                              void* d_out, int out_size, void* d_ws, size_t ws_size,
                              hipStream_t stream) {
  const int* g1 = (const int*)d_in[0];
  const int* g2 = (const int*)d_in[1];
  const float* x1 = (const float*)d_in[2];
  const float* x2 = (const float*)d_in[3];
  const float* W11 = (const float*)d_in[4];
  const float* b11 = (const float*)d_in[5];
  const float* W12 = (const float*)d_in[6];
  const float* b12 = (const float*)d_in[7];
  const float* W21 = (const float*)d_in[8];
  const float* b21 = (const float*)d_in[9];
  const float* W22 = (const float*)d_in[10];
  const float* b22 = (const float*)d_in[11];
  const float* q1 = (const float*)d_in[12];
  const float* k1 = (const float*)d_in[13];
  const float* v1 = (const float*)d_in[14];
  const float* q2 = (const float*)d_in[15];
  const float* k2 = (const float*)d_in[16];
  const float* v2 = (const float*)d_in[17];

  // d_out (256 MB) is scratch for everything that dies before k_outer.
  char* ob = (char*)d_out;
  const size_t MB = 1u << 20;
  int* srcl1 = (int*)(ob + 0 * MB);
  int* srcl2 = (int*)(ob + 1 * MB);
  char* small = ob + 2 * MB;
  int* ideg1 = (int*)(small);
  int* ideg2 = (int*)(small + (32u << 10));
  int* off1 = (int*)(small + (64u << 10));
  int* off2 = (int*)(small + (128u << 10));
  int* cur1 = (int*)(small + (192u << 10));
  int* cur2 = (int*)(small + (256u << 10));
  float* dinv1 = (float*)(small + (320u << 10));
  float* dinv2 = (float*)(small + (384u << 10));
  short* whi = (short*)(ob + 3 * MB);            // 240KB
  short* wlo = (short*)(ob + 3 * MB + (512u << 10));
  short* a1hi = (short*)(ob + 4 * MB);           // 2MB each
  short* a1lo = (short*)(ob + 6 * MB);
  short* a2hi = (short*)(ob + 8 * MB);
  short* a2lo = (short*)(ob + 10 * MB);
  short* h1hi = (short*)(ob + 12 * MB);          // 4MB each
  short* h1lo = (short*)(ob + 16 * MB);
  short* h2hi = (short*)(ob + 20 * MB);
  short* h2lo = (short*)(ob + 24 * MB);
  float* tbuf1 = (float*)(ob + 28 * MB);         // 2MB each
  float* tbuf2 = (float*)(ob + 30 * MB);
  short* g1hi = (short*)(ob + 32 * MB);          // 1MB each
  short* g1lo = (short*)(ob + 33 * MB);
  short* g2hi = (short*)(ob + 34 * MB);
  short* g2lo = (short*)(ob + 35 * MB);
  short* Qhi = (short*)(ob + 36 * MB);
  short* Qlo = (short*)(ob + 37 * MB);
  short* Khi = (short*)(ob + 38 * MB);
  short* Klo = (short*)(ob + 39 * MB);
  short* Vthi = (short*)(ob + 40 * MB);
  short* Vtlo = (short*)(ob + 41 * MB);
  float* Opart = (float*)(ob + 42 * MB);         // 16MB
  float* mpart = (float*)(ob + 58 * MB);
  float* lpart = (float*)(ob + 58 * MB + (256u << 10));
  // d_ws: persists into k_outer
  short* o1hi = (short*)d_ws;
  short* o1lo = (short*)((char*)d_ws + 1 * MB);
  short* o2hi = (short*)((char*)d_ws + 2 * MB);
  short* o2lo = (short*)((char*)d_ws + 3 * MB);

  hipMemsetAsync(ideg1, 0, 64u << 10, stream);  // covers ideg1+ideg2
  k_count2<<<dim3(1024, 2), 256, 0, stream>>>(g1 + NE, g2 + NE, ideg1, ideg2);
  k_scan2<<<2, 1024, 0, stream>>>(ideg1, off1, cur1, dinv1, ideg2, off2, cur2, dinv2);
  k_fill2<<<dim3(1024, 2), 256, 0, stream>>>(g1, g1 + NE, cur1, srcl1,
                                             g2, g2 + NE, cur2, srcl2);
  k_split_w<<<dim3(128, 10), 256, 0, stream>>>(W11, W21, W12, W22, q1, k1, v1,
                                               q2, k2, v2, whi, wlo);

  // GCN (both branches fused per stage)
  k_agg1d<<<dim3(2048, 2), 256, 0, stream>>>(x1, x2, off1, srcl1, dinv1,
                                             off2, srcl2, dinv2,
                                             a1hi, a1lo, a2hi, a2lo);
  k_gemmL1<<<dim3(512, 4, 2), 64, 0, stream>>>(a1hi, a1lo, a2hi, a2lo, whi, wlo,
                                               b11, b21, h1hi, h1lo, h2hi, h2lo);
  k_gemmL2<<<dim3(512, 2), 64, 0, stream>>>(h1hi, h1lo, h2hi, h2lo, whi, wlo,
                                            tbuf1, tbuf2);
  k_agg2d<<<dim3(2048, 2), 256, 0, stream>>>(tbuf1, tbuf2, off1, srcl1, dinv1,
                                             off2, srcl2, dinv2, b12, b22,
                                             g1hi, g1lo, g2hi, g2lo);

  // cross attention 1: Q=g1@q1, K=g2@k1, V=g1@v1 -> o1
  k_qkv<<<dim3(512, 3), 64, 0, stream>>>(g1hi, g1lo, g2hi, g2lo, g1hi, g1lo,
                                         whi, wlo, 98304, 102400, 106496,
                                         Qhi, Qlo, Khi, Klo, Vthi, Vtlo);
  k_attn_v4<<<dim3(64, NCH), 512, 0, stream>>>(Qhi, Qlo, Khi, Klo, Vthi, Vtlo,
                                               Opart, mpart, lpart);
  k_comb<<<2048, 256, 0, stream>>>(Opart, mpart, lpart, o1hi, o1lo);

  // cross attention 2: Q=g2@q2, K=o1@k2, V=g2@v2 -> o2
  k_qkv<<<dim3(512, 3), 64, 0, stream>>>(g2hi, g2lo, o1hi, o1lo, g2hi, g2lo,
                                         whi, wlo, 110592, 114688, 118784,
                                         Qhi, Qlo, Khi, Klo, Vthi, Vtlo);
  k_attn_v4<<<dim3(64, NCH), 512, 0, stream>>>(Qhi, Qlo, Khi, Klo, Vthi, Vtlo,
                                               Opart, mpart, lpart);
  k_comb<<<2048, 256, 0, stream>>>(Opart, mpart, lpart, o2hi, o2lo);

  // logits = o1 @ o2^T -> d_out (overwrites all scratch)
  k_outer<<<dim3(128, 16), 256, 0, stream>>>(o1hi, o1lo, o2hi, o2lo, (float*)d_out);

  (void)in_sizes; (void)n_in; (void)out_size; (void)ws_size;
}